// Round 13
// baseline (727.429 us; speedup 1.0000x reference)
//
#include <hip/hip_runtime.h>
#include <math.h>

typedef unsigned short ushort_t;
typedef unsigned long long u64;
typedef unsigned int uint32;

#define B_ 8
#define N_ 4096
#define S_ 1024
#define K_ 32
#define C_ 128
#define NCOL1 (B_*S_*K_)   // 262144
#define NCOL2 (B_*S_)      // 8192
#define EPS_ 1e-5f

typedef short s16x8 __attribute__((ext_vector_type(8)));
typedef float f32x4 __attribute__((ext_vector_type(4)));

__device__ __forceinline__ float bf2f(ushort_t u){ return __uint_as_float(((uint32)u)<<16); }
__device__ __forceinline__ ushort_t f2bf(float f){
    uint32 x = __float_as_uint(f);
    return (ushort_t)((x + 0x7FFFu + ((x>>16)&1u)) >> 16);
}
__device__ __forceinline__ float gelu_f(float v){
    float az = fabsf(v)*0.70710678118654752f;
    float t  = __builtin_amdgcn_rcpf(fmaf(0.3275911f, az, 1.0f));
    float p  = fmaf(fmaf(fmaf(fmaf(1.061405429f, t, -1.453152027f), t, 1.421413741f), t,
                   -0.284496736f), t, 0.254829592f)*t;
    float e  = __expf(-az*az);
    float er = fmaf(-p, e, 1.0f);
    float s  = (v < 0.0f) ? -er : er;
    return 0.5f*v*(1.0f+s);
}
__device__ __forceinline__ u64 shfl_xor_u64(u64 v, int m){
    int lo = __shfl_xor((int)(v & 0xFFFFFFFFull), m, 64);
    int hi = __shfl_xor((int)(v >> 32), m, 64);
    return (((u64)(uint32)hi) << 32) | (uint32)lo;
}
__device__ __forceinline__ void gl_lds16(const char* gp, char* lp){
    __builtin_amdgcn_global_load_lds((const __attribute__((address_space(1))) void*)gp,
                                     (__attribute__((address_space(3))) void*)lp, 16, 0, 0);
}
#define PIN_VMCNT0() do{ __builtin_amdgcn_sched_barrier(0); \
                         asm volatile("s_waitcnt vmcnt(0)" ::: "memory"); \
                         __builtin_amdgcn_sched_barrier(0); }while(0)

// ---------------- transpose x (B,64,N) -> xTb (B,N,64) bf16 ----------------
__global__ __launch_bounds__(256) void transpose_kernel(const float* __restrict__ x, ushort_t* __restrict__ xTb){
    __shared__ float t[64][65];
    int b  = blockIdx.x >> 6;
    int n0 = (blockIdx.x & 63) * 64;
    int tx = threadIdx.x & 63, ty = threadIdx.x >> 6;
    #pragma unroll
    for (int i=0;i<16;i++){
        int c = i*4 + ty;
        t[c][tx] = x[((long)(b*64 + c))*N_ + n0 + tx];
    }
    __syncthreads();
    #pragma unroll
    for (int i=0;i<16;i++){
        int n = i*4 + ty;
        xTb[((long)(b*N_ + n0 + n))*64 + tx] = f2bf(t[tx][n]);
    }
}

// ---------------- KNN: 2-level radix select (1024/4096 bins), exact ----------------
__global__ __launch_bounds__(256) void knn_kernel(const float* __restrict__ xyz, const int* __restrict__ fps,
                                                  int* __restrict__ idxg, float* __restrict__ newxyz){
    __shared__ uint32 hist[4096];
    __shared__ u64    cand[1024];
    __shared__ u64    out_keys[64];
    __shared__ uint32 csum[256];
    __shared__ uint32 wtot[4];
    __shared__ uint32 shv[8];
    __shared__ u64    wred[4];
    __shared__ u64    winner;

    int tid = threadIdx.x;
    int wv = tid >> 6, l = tid & 63;
    int bs = blockIdx.x;
    int b  = bs >> 10;
    int qi = fps[bs];
    const float* qb = xyz + ((long)b*N_ + qi)*3;
    float qx = qb[0], qy = qb[1], qz = qb[2];
    if (tid < 3) newxyz[(long)bs*3 + tid] = qb[tid];
    const float* xb = xyz + (long)b*N_*3;

    for (int i=tid;i<1024;i+=256) hist[i]=0;
    if (tid < 8) shv[tid]=0;
    __syncthreads();

    uint32 dbits[16];
    #pragma unroll
    for (int i=0;i<16;i++){
        int n = i*256 + tid;
        float dx = xb[n*3+0]-qx, dy = xb[n*3+1]-qy, dz = xb[n*3+2]-qz;
        float d = dx*dx + dy*dy + dz*dz;
        dbits[i] = __float_as_uint(d);
        atomicAdd(&hist[dbits[i]>>21], 1u);
    }
    __syncthreads();

    {
        uint32 h4[4]; uint32 csumv=0;
        #pragma unroll
        for (int i=0;i<4;i++){ h4[i]=hist[tid*4+i]; csumv+=h4[i]; }
        uint32 sc = csumv;
        #pragma unroll
        for (int off=1; off<64; off<<=1){ uint32 o=__shfl_up(sc,off,64); if (l>=off) sc+=o; }
        if (l==63) wtot[wv]=sc;
        csum[tid]=sc;
        __syncthreads();
        uint32 base=0;
        for (int w2=0; w2<wv; w2++) base += wtot[w2];
        uint32 cum = base + csum[tid] - csumv;
        #pragma unroll
        for (int i=0;i<4;i++){
            if (cum <= 31u && 31u < cum + h4[i]){ shv[0]=(uint32)(tid*4+i); shv[1]=cum; }
            cum += h4[i];
        }
    }
    __syncthreads();
    uint32 b1 = shv[0], cl1 = shv[1];

    for (int i=tid;i<4096;i+=256) hist[i]=0;
    __syncthreads();
    #pragma unroll
    for (int i=0;i<16;i++){
        uint32 u = dbits[i];
        if ((u>>21)==b1) atomicAdd(&hist[(u>>9)&0xFFFu], 1u);
    }
    __syncthreads();

    uint32 r2 = 31u - cl1;
    {
        uint32 h[16]; uint32 csumv=0;
        #pragma unroll
        for (int i=0;i<16;i++){ h[i]=hist[tid*16+i]; csumv += h[i]; }
        uint32 sc = csumv;
        #pragma unroll
        for (int off=1; off<64; off<<=1){ uint32 o=__shfl_up(sc,off,64); if (l>=off) sc+=o; }
        if (l==63) wtot[wv]=sc;
        csum[tid]=sc;
        __syncthreads();
        uint32 base=0;
        for (int w2=0; w2<wv; w2++) base += wtot[w2];
        uint32 cum = base + csum[tid] - csumv;
        #pragma unroll
        for (int i=0;i<16;i++){
            if (cum <= r2 && r2 < cum + h[i]){ shv[2]=(uint32)(tid*16+i); shv[3]=cum; }
            cum += h[i];
        }
    }
    __syncthreads();
    uint32 b2 = shv[2], cl2 = shv[3];
    uint32 nless = cl1 + cl2;

    #pragma unroll
    for (int i=0;i<16;i++){
        uint32 u = dbits[i];
        int n = i*256 + tid;
        uint32 bb1 = u >> 21;
        if (bb1 > b1) continue;
        u64 key = (((u64)u)<<32) | (uint32)n;
        if (bb1 < b1){
            uint32 p = atomicAdd(&shv[4],1u); out_keys[p] = key;
        } else {
            uint32 bb2 = (u>>9)&0xFFFu;
            if (bb2 < b2){ uint32 p = atomicAdd(&shv[4],1u); out_keys[p] = key; }
            else if (bb2 == b2){ uint32 p = atomicAdd(&shv[5],1u); if (p < 1024u) cand[p] = key; }
        }
    }
    __syncthreads();

    if (shv[5] > 1024u){
        uint32 alive = 0xFFFFu;
        for (int r=0;r<K_;r++){
            u64 lmin = ~0ull;
            #pragma unroll
            for (int i=0;i<16;i++){
                u64 k = (((u64)dbits[i])<<32) | (uint32)(i*256+tid);
                if (((alive>>i)&1u) && k < lmin) lmin = k;
            }
            #pragma unroll
            for (int off=32; off>=1; off>>=1){
                u64 o = shfl_xor_u64(lmin, off);
                if (o < lmin) lmin = o;
            }
            if (l == 0) wred[wv] = lmin;
            __syncthreads();
            if (tid == 0){
                u64 m = wred[0];
                if (wred[1]<m) m=wred[1];
                if (wred[2]<m) m=wred[2];
                if (wred[3]<m) m=wred[3];
                winner = m;
                idxg[(long)bs*K_ + r] = (int)(m & 0xFFFFFFFFull);
            }
            __syncthreads();
            u64 w = winner;
            #pragma unroll
            for (int i=0;i<16;i++){
                u64 k = (((u64)dbits[i])<<32) | (uint32)(i*256+tid);
                if (k == w) alive &= ~(1u<<i);
            }
        }
    } else if (wv == 0){
        uint32 cb   = shv[5];
        uint32 need = 32u - nless;
        for (uint32 r=0; r<need; r++){
            u64 lmin = ~0ull;
            for (uint32 s=l; s<cb; s+=64){ u64 kk = cand[s]; if (kk < lmin) lmin = kk; }
            #pragma unroll
            for (int off=32; off>=1; off>>=1){
                u64 o = shfl_xor_u64(lmin, off);
                if (o < lmin) lmin = o;
            }
            for (uint32 s=l; s<cb; s+=64){ if (cand[s]==lmin) cand[s] = ~0ull; }
            if (l==0) out_keys[nless + r] = lmin;
        }
        u64 key = (l < 32) ? out_keys[l] : ~0ull;
        #pragma unroll
        for (uint32 k=2; k<=64; k<<=1){
            bool dir = ((l & k)==0);
            #pragma unroll
            for (uint32 j=k>>1; j>=1; j>>=1){
                u64 o = shfl_xor_u64(key, j);
                bool lower = ((l & j)==0);
                u64 mn = (key < o) ? key : o;
                u64 mx = (key < o) ? o : key;
                key = (lower == dir) ? mn : mx;
            }
        }
        if (l < 32) idxg[(long)bs*K_ + l] = (int)(key & 0xFFFFFFFFull);
    }
}

// ---------------- weights f32 -> bf16 (10 mats) + UW/VW halves of W1 ----------------
__global__ __launch_bounds__(256) void wcvt_kernel(const float* __restrict__ pcw, const float* __restrict__ pfw,
                                                   const float* __restrict__ qcw, const float* __restrict__ qfw,
                                                   ushort_t* __restrict__ Wb, ushort_t* __restrict__ UW,
                                                   ushort_t* __restrict__ VW){
    int i = blockIdx.x*256 + threadIdx.x;   // 0 .. 180223
    if (i < 163840){
        int mat = i >> 14;
        int r = i & 16383;
        float v;
        if (mat < 4)       v = pcw[i];
        else if (mat == 4) v = pfw[r];
        else if (mat < 9)  v = qcw[i - 5*16384];
        else               v = qfw[r];
        Wb[i] = f2bf(v);
    } else {
        int j = i - 163840;                 // 0..16383
        int jj = j & 8191;
        int oc = jj >> 6, c = jj & 63;
        if (j < 8192) UW[jj] = f2bf(pcw[oc*128 + c]);
        else          VW[jj] = f2bf(pcw[oc*128 + 64 + c] - pcw[oc*128 + c]);
    }
}

// ---------------- U = xTb x UW^T ; V2[bs] = VW x xTb[fps[bs]] (K=64 GEMM) ----------------
__global__ __launch_bounds__(256) void uv_gemm(const ushort_t* __restrict__ xTb, const int* __restrict__ fps,
                                               const ushort_t* __restrict__ UW, const ushort_t* __restrict__ VW,
                                               ushort_t* __restrict__ U, ushort_t* __restrict__ V2){
    int tid = threadIdx.x;
    int w = tid >> 6, l = tid & 63;
    int l15 = l & 15, l4 = l >> 4;
    bool isV = blockIdx.x >= 256;
    int base = (isV ? (int)(blockIdx.x - 256) : (int)blockIdx.x)*128 + w*32;
    const ushort_t* Wh = isV ? VW : UW;
    ushort_t* out = isV ? V2 : U;

    long xrow[2];
    #pragma unroll
    for (int n=0;n<2;n++){
        int r = base + n*16 + l15;
        if (isV){ int b = r >> 10; xrow[n] = ((long)(b<<12) + fps[r]); }
        else    { xrow[n] = r; }
    }
    f32x4 acc[8][2] = {};
    #pragma unroll
    for (int ks=0; ks<2; ks++){
        int kl = ks*32 + l4*8;
        s16x8 af[8];
        #pragma unroll
        for (int m=0;m<8;m++)
            af[m] = *(const s16x8*)(Wh + (m*16 + l15)*64 + kl);
        s16x8 bv[2];
        #pragma unroll
        for (int n=0;n<2;n++)
            bv[n] = *(const s16x8*)(xTb + xrow[n]*64 + kl);
        #pragma unroll
        for (int m=0;m<8;m++)
            #pragma unroll
            for (int n=0;n<2;n++)
                acc[m][n] = __builtin_amdgcn_mfma_f32_16x16x32_bf16(af[m], bv[n], acc[m][n], 0, 0, 0);
    }
    #pragma unroll
    for (int n=0;n<2;n++){
        long radr = (long)(base + n*16 + l15)*C_;
        #pragma unroll
        for (int m=0;m<8;m++){
            f32x4 a = acc[m][n];
            uint2 st;
            st.x = (((uint32)f2bf(a[1]))<<16) | f2bf(a[0]);
            st.y = (((uint32)f2bf(a[3]))<<16) | f2bf(a[2]);
            *(uint2*)(out + radr + m*16 + l4*4) = st;
        }
    }
}

// ---------------- GADD: T1[col][oc] = U[idx[col]][oc] + V2[col>>5][oc], + BN stats ----------
__global__ __launch_bounds__(256) void gadd_kernel(const ushort_t* __restrict__ U, const ushort_t* __restrict__ V2,
                                                   const int* __restrict__ idxg, ushort_t* __restrict__ out,
                                                   float* __restrict__ pb, int nb){
    __shared__ float sL[4][128], qL[4][128];
    int tid = threadIdx.x;
    int w = tid >> 6, l = tid & 63;
    int l15 = l & 15, l4 = l >> 4;
    long col0 = ((long)blockIdx.x << 7) + ((long)w << 5);
    int bs = (int)(col0 >> 5);
    int b  = bs >> 10;
    const ushort_t* vrow = V2 + (long)bs*C_;

    f32x4 acc[8][2];
    #pragma unroll
    for (int n=0;n<2;n++){
        int nn = idxg[col0 + n*16 + l15];
        const ushort_t* urow = U + ((long)(b*4096) + nn)*C_;
        #pragma unroll
        for (int m=0;m<8;m++){
            int oc0 = m*16 + l4*4;
            uint2 uu = *(const uint2*)(urow + oc0);
            uint2 vv = *(const uint2*)(vrow + oc0);
            acc[m][n][0] = bf2f((ushort_t)(uu.x & 0xFFFFu)) + bf2f((ushort_t)(vv.x & 0xFFFFu));
            acc[m][n][1] = bf2f((ushort_t)(uu.x >> 16))     + bf2f((ushort_t)(vv.x >> 16));
            acc[m][n][2] = bf2f((ushort_t)(uu.y & 0xFFFFu)) + bf2f((ushort_t)(vv.y & 0xFFFFu));
            acc[m][n][3] = bf2f((ushort_t)(uu.y >> 16))     + bf2f((ushort_t)(vv.y >> 16));
        }
    }
    #pragma unroll
    for (int n=0;n<2;n++){
        long cadr = (col0 + n*16 + l15)*C_;
        #pragma unroll
        for (int m=0;m<8;m++){
            f32x4 a = acc[m][n];
            uint2 st;
            st.x = (((uint32)f2bf(a[1]))<<16) | f2bf(a[0]);
            st.y = (((uint32)f2bf(a[3]))<<16) | f2bf(a[2]);
            *(uint2*)(out + cadr + m*16 + l4*4) = st;
        }
    }
    #pragma unroll
    for (int m=0;m<8;m++){
        #pragma unroll
        for (int r=0;r<4;r++){
            float a0=acc[m][0][r], a1=acc[m][1][r];
            float s = a0+a1;
            float q = a0*a0+a1*a1;
            #pragma unroll
            for (int off=1; off<16; off<<=1){
                s += __shfl_xor(s, off, 64);
                q += __shfl_xor(q, off, 64);
            }
            if (l15 == 0){
                sL[w][m*16 + l4*4 + r] = s;
                qL[w][m*16 + l4*4 + r] = q;
            }
        }
    }
    __syncthreads();
    if (tid < 128){
        float s = sL[0][tid] + sL[1][tid] + sL[2][tid] + sL[3][tid];
        float q = qL[0][tid] + qL[1][tid] + qL[2][tid] + qL[3][tid];
        pb[(long)tid*nb + blockIdx.x]       = s;
        pb[(long)(128+tid)*nb + blockIdx.x] = q;
    }
}

// ---------------- pipelined MFMA conv: 64-col tiles, NT=2, wave-private dbuf fill ----------
// Wave w owns cols [tile*64 + w*16, +16): fills AND computes them -> no cross-wave LDS
// dependency -> no barrier in the tile loop. Per tile: issue fill(t+1)+a2(t+1), compute t
// (fill t+1 in flight under the VALU/MFMA phase), store t direct, pinned vmcnt(0), swap.
// MODE: 0 RAW | 1 PRE gelu(bn(in1)) | 2 RESID gelu(bn(in1)+in2), aux-store
//       4 RESID_VIRT (in2 = feature gather from xTb/idx/fps), aux-store
template<int MODE, int NT>
__global__ __launch_bounds__(256, 4) void conv_pipe(const ushort_t* in1, const ushort_t* in2, ushort_t* aux,
        ushort_t* out, const ushort_t* __restrict__ Wb, const float* __restrict__ scsh_g,
        const ushort_t* __restrict__ xTb, const int* __restrict__ idxg, const int* __restrict__ fps,
        float* __restrict__ pb, int nb){
    __shared__ ushort_t inT[2][8192];     // 2 x 16 KB tile dbuf
    __shared__ float ss[256];
    __shared__ float sL[4][128], qL[4][128];
    int tid = threadIdx.x;
    int w = tid >> 6, l = tid & 63;
    int l15 = l & 15, l4 = l >> 4;
    int G = gridDim.x;

    // per-wave stats rows init (wave-private, no barrier needed)
    sL[w][l] = 0.f; sL[w][64+l] = 0.f;
    qL[w][l] = 0.f; qL[w][64+l] = 0.f;

    // fill tile 0 -> buf 0 (wave-private 4KB)
    {
        const char* gt = (const char*)in1 + ((long)blockIdx.x << 14);
        #pragma unroll
        for (int i=0;i<4;i++){
            int p = (w<<12) + (i<<10) + (l<<4);
            int src = p ^ (((p>>8)&7)<<4);
            gl_lds16(gt + src, (char*)&inT[0][0] + (w<<12) + (i<<10));
        }
    }
    // residual operand for tile 0
    s16x8 a2cur[4], a2nxt[4];
    if (MODE == 2){
        long c0 = ((long)blockIdx.x << 6) + (w<<4);
        #pragma unroll
        for (int ks=0;ks<4;ks++)
            a2cur[ks] = *(const s16x8*)(in2 + (c0 + l15)*C_ + ks*32 + l4*8);
    }
    if (MODE == 4){
        long c0 = ((long)blockIdx.x << 6) + (w<<4);
        int bs = (int)(c0 >> 5);
        int b  = bs >> 10;
        int cc = fps[bs];
        const ushort_t* crow = xTb + ((long)(b<<12) + cc)*64;
        s16x8 cv0 = *(const s16x8*)(crow + l4*8);
        s16x8 cv1 = *(const s16x8*)(crow + 32 + l4*8);
        int nn = idxg[c0 + l15];
        const ushort_t* prow = xTb + ((long)(b<<12) + nn)*64;
        s16x8 p0 = *(const s16x8*)(prow + l4*8);
        s16x8 p1 = *(const s16x8*)(prow + 32 + l4*8);
        s16x8 d0, d1;
        #pragma unroll
        for (int e=0;e<8;e++){
            d0[e] = (short)f2bf(bf2f((ushort_t)p0[e]) - bf2f((ushort_t)cv0[e]));
            d1[e] = (short)f2bf(bf2f((ushort_t)p1[e]) - bf2f((ushort_t)cv1[e]));
        }
        a2cur[0]=d0; a2cur[1]=d1; a2cur[2]=cv0; a2cur[3]=cv1;
    }
    if (MODE != 0) ss[tid] = scsh_g[tid];
    __syncthreads();    // ss visible; drains fill0 (prologue only)

    #pragma unroll
    for (int t=0; t<NT; t++){
        long tile = (long)t*G + blockIdx.x;
        long col0 = (tile << 6) + (w<<4);

        // ---- prefetch tile t+1 (stays in flight under compute t) ----
        if (t+1 < NT){
            long tn = tile + G;
            const char* gt = (const char*)in1 + (tn << 14);
            #pragma unroll
            for (int i=0;i<4;i++){
                int p = (w<<12) + (i<<10) + (l<<4);
                int src = p ^ (((p>>8)&7)<<4);
                gl_lds16(gt + src, (char*)&inT[(t+1)&1][0] + (w<<12) + (i<<10));
            }
            if (MODE == 2){
                long c1 = (tn << 6) + (w<<4);
                #pragma unroll
                for (int ks=0;ks<4;ks++)
                    a2nxt[ks] = *(const s16x8*)(in2 + (c1 + l15)*C_ + ks*32 + l4*8);
            }
            if (MODE == 4){
                long c1 = (tn << 6) + (w<<4);
                int bs = (int)(c1 >> 5);
                int b  = bs >> 10;
                int cc = fps[bs];
                const ushort_t* crow = xTb + ((long)(b<<12) + cc)*64;
                s16x8 cv0 = *(const s16x8*)(crow + l4*8);
                s16x8 cv1 = *(const s16x8*)(crow + 32 + l4*8);
                int nn = idxg[c1 + l15];
                const ushort_t* prow = xTb + ((long)(b<<12) + nn)*64;
                s16x8 p0 = *(const s16x8*)(prow + l4*8);
                s16x8 p1 = *(const s16x8*)(prow + 32 + l4*8);
                s16x8 d0, d1;
                #pragma unroll
                for (int e=0;e<8;e++){
                    d0[e] = (short)f2bf(bf2f((ushort_t)p0[e]) - bf2f((ushort_t)cv0[e]));
                    d1[e] = (short)f2bf(bf2f((ushort_t)p1[e]) - bf2f((ushort_t)cv1[e]));
                }
                a2nxt[0]=d0; a2nxt[1]=d1; a2nxt[2]=cv0; a2nxt[3]=cv1;
            }
        }

        // ---- compute tile t from buf t&1 (wave-private 4KB) ----
        const char* lb = (const char*)&inT[t&1][0];
        f32x4 acc[8] = {};
        #pragma unroll
        for (int ks=0; ks<4; ks++){
            int kl = ks*32 + l4*8;
            s16x8 af[8];
            #pragma unroll
            for (int m=0;m<8;m++)
                af[m] = *(const s16x8*)(Wb + (m*16 + l15)*C_ + kl);
            int q  = ((w<<4) + l15)*256 + ks*64 + (l4<<4);
            int qs = q ^ (((q>>8)&7)<<4);
            s16x8 v = *(const s16x8*)(lb + qs);
            if (MODE != 0){
                float sc[8], sh[8];
                const float4* sp = (const float4*)(&ss[kl*2]);
                float4 s0 = sp[0], s1 = sp[1], s2 = sp[2], s3 = sp[3];
                sc[0]=s0.x; sh[0]=s0.y; sc[1]=s0.z; sh[1]=s0.w;
                sc[2]=s1.x; sh[2]=s1.y; sc[3]=s1.z; sh[3]=s1.w;
                sc[4]=s2.x; sh[4]=s2.y; sc[5]=s2.z; sh[5]=s2.w;
                sc[6]=s3.x; sh[6]=s3.y; sc[7]=s3.z; sh[7]=s3.w;
                if (MODE == 1){
                    #pragma unroll
                    for (int e=0;e<8;e++){
                        float f = gelu_f(fmaf(bf2f((ushort_t)v[e]), sc[e], sh[e]));
                        v[e] = (short)f2bf(f);
                    }
                } else {
                    s16x8 a = a2cur[ks];
                    #pragma unroll
                    for (int e=0;e<8;e++){
                        float f = gelu_f(fmaf(bf2f((ushort_t)v[e]), sc[e], sh[e]) + bf2f((ushort_t)a[e]));
                        v[e] = (short)f2bf(f);
                    }
                }
                if (MODE == 2 || MODE == 4)
                    *(s16x8*)(aux + (col0 + l15)*C_ + kl) = v;     // wave-private col, safe
            }
            #pragma unroll
            for (int m=0;m<8;m++)
                acc[m] = __builtin_amdgcn_mfma_f32_16x16x32_bf16(af[m], v, acc[m], 0, 0, 0);
        }

        // ---- out store direct (L2 merges the wave's contiguous 4KB region) ----
        {
            long cadr = (col0 + l15)*C_;
            #pragma unroll
            for (int m=0;m<8;m++){
                f32x4 a = acc[m];
                uint2 st;
                st.x = (((uint32)f2bf(a[1]))<<16) | f2bf(a[0]);
                st.y = (((uint32)f2bf(a[3]))<<16) | f2bf(a[2]);
                *(uint2*)(out + cadr + m*16 + l4*4) = st;
            }
        }

        // ---- BN stats accumulate (wave-private LDS rows, no barrier) ----
        #pragma unroll
        for (int m=0;m<8;m++){
            #pragma unroll
            for (int r=0;r<4;r++){
                float s = acc[m][r];
                float q = s*s;
                #pragma unroll
                for (int off=1; off<16; off<<=1){
                    s += __shfl_xor(s, off, 64);
                    q += __shfl_xor(q, off, 64);
                }
                if (l15 == 0){
                    sL[w][m*16 + l4*4 + r] += s;
                    qL[w][m*16 + l4*4 + r] += q;
                }
            }
        }

        if (t+1 < NT){
            PIN_VMCNT0();              // fill(t+1)+a2(t+1) complete before next compute
            if (MODE == 2 || MODE == 4){
                #pragma unroll
                for (int ks=0;ks<4;ks++) a2cur[ks] = a2nxt[ks];
            }
        }
    }

    __syncthreads();
    if (tid < 128){
        float s = sL[0][tid] + sL[1][tid] + sL[2][tid] + sL[3][tid];
        float q = qL[0][tid] + qL[1][tid] + qL[2][tid] + qL[3][tid];
        pb[(long)tid*nb + blockIdx.x]       = s;
        pb[(long)(128+tid)*nb + blockIdx.x] = q;
    }
}

// ---------------- reduce partials[256][nb] -> (scale, shift) ----------------
__global__ __launch_bounds__(256) void reduce_fin_kernel(const float* __restrict__ pb, float* __restrict__ scsh,
                                                         const float* __restrict__ g, const float* __restrict__ bb,
                                                         float inv_cnt, int nb){
    int oc = blockIdx.x;
    float s=0.f, q=0.f;
    for (int b=threadIdx.x; b<nb; b+=256){
        s += pb[(long)oc*nb + b];
        q += pb[(long)(128+oc)*nb + b];
    }
    __shared__ float ls[256], lq[256];
    ls[threadIdx.x]=s; lq[threadIdx.x]=q;
    __syncthreads();
    #pragma unroll
    for (int st_=128; st_>0; st_>>=1){
        if (threadIdx.x < st_){ ls[threadIdx.x]+=ls[threadIdx.x+st_]; lq[threadIdx.x]+=lq[threadIdx.x+st_]; }
        __syncthreads();
    }
    if (threadIdx.x==0){
        float mean = ls[0]*inv_cnt;
        float var  = lq[0]*inv_cnt - mean*mean;
        float sc   = g[oc]*rsqrtf(var + EPS_);
        scsh[oc*2+0] = sc;
        scsh[oc*2+1] = bb[oc] - mean*sc;
    }
}

// ---------------- pool with fused resid: A2[bs][c] = max_k gelu(bn(T)+X) ----------------
__global__ __launch_bounds__(256) void pool_kernel(const ushort_t* __restrict__ T, const ushort_t* __restrict__ X,
                                                   const float* __restrict__ scsh, ushort_t* __restrict__ A2){
    long p  = (long)blockIdx.x*256 + threadIdx.x;
    long bs = p >> 6;
    int  c0 = ((int)p & 63)*2;
    float sc0=scsh[c0*2], sh0=scsh[c0*2+1], sc1=scsh[c0*2+2], sh1=scsh[c0*2+3];
    const ushort_t* tb = T + (bs*K_)*(long)C_ + c0;
    const ushort_t* xv = X + (bs*K_)*(long)C_ + c0;
    float m0 = -1e30f, m1 = -1e30f;
    #pragma unroll 4
    for (int k=0;k<K_;k++){
        uint32 tv = *(const uint32*)(tb + (long)k*C_);
        uint32 av = *(const uint32*)(xv + (long)k*C_);
        float v0 = gelu_f(fmaf(bf2f((ushort_t)(tv & 0xFFFFu)), sc0, sh0) + bf2f((ushort_t)(av & 0xFFFFu)));
        float v1 = gelu_f(fmaf(bf2f((ushort_t)(tv >> 16)),     sc1, sh1) + bf2f((ushort_t)(av >> 16)));
        m0 = fmaxf(m0, v0);
        m1 = fmaxf(m1, v1);
    }
    uint32 o = (((uint32)f2bf(m1))<<16) | f2bf(m0);
    *(uint32*)(A2 + bs*C_ + c0) = o;
}

// ---------------- out2: y[b][c][s] = gelu(bn(T)+X), LDS-tiled, coalesced ----------------
__global__ __launch_bounds__(256) void out2_kernel(const ushort_t* __restrict__ T, const ushort_t* __restrict__ X,
                                                   const float* __restrict__ scsh_g, float* __restrict__ y){
    __shared__ ushort_t Ts[16384];
    __shared__ ushort_t Xs[16384];
    __shared__ float ss[256];
    int tid = threadIdx.x, w = tid>>6, l = tid&63;
    int blk = blockIdx.x;

    {
        const char* gt = (const char*)(T + ((long)blk << 7)*C_);
        const char* gx = (const char*)(X + ((long)blk << 7)*C_);
        #pragma unroll
        for (int i=0;i<8;i++){
            int p = i*4096 + w*1024 + l*16;
            int src = p ^ (((p>>8)&7)<<4);
            gl_lds16(gt + src, (char*)Ts + i*4096 + w*1024);
            gl_lds16(gx + src, (char*)Xs + i*4096 + w*1024);
        }
    }
    ss[tid] = scsh_g[tid];
    __syncthreads();

    int b  = blk >> 3;
    int s0 = (blk & 7) * 128;
    int colL = tid & 127;
    int rep  = tid >> 7;
    #pragma unroll
    for (int cb=0; cb<8; cb++){
        int q  = colL*256 + rep*128 + cb*16;
        int qs = q ^ (((q>>8)&7)<<4);
        s16x8 tvv = *(const s16x8*)((char*)Ts + qs);
        s16x8 xvv = *(const s16x8*)((char*)Xs + qs);
        #pragma unroll
        for (int e=0;e<8;e++){
            int c = rep*64 + cb*8 + e;
            float f = gelu_f(fmaf(bf2f((ushort_t)tvv[e]), ss[c*2], ss[c*2+1]) + bf2f((ushort_t)xvv[e]));
            y[((long)(b*C_ + c))*S_ + s0 + colL] = f;
        }
    }
}

// ---------------- host ----------------
extern "C" void kernel_launch(void* const* d_in, const int* in_sizes, int n_in,
                              void* d_out, int out_size, void* d_ws, size_t ws_size,
                              hipStream_t stream){
    const float* xyz        = (const float*)d_in[0];
    const float* x          = (const float*)d_in[1];
    const int*   fps        = (const int*)d_in[2];
    const float* pre_bn_g   = (const float*)d_in[4];
    const float* pre_bn_b   = (const float*)d_in[5];
    const float* pre_ffn_g  = (const float*)d_in[7];
    const float* pre_ffn_b  = (const float*)d_in[8];
    const float* pos_bn_g   = (const float*)d_in[10];
    const float* pos_bn_b   = (const float*)d_in[11];
    const float* pos_ffn_g  = (const float*)d_in[13];
    const float* pos_ffn_b  = (const float*)d_in[14];

    float* out_xyz = (float*)d_out;
    float* out_y   = (float*)d_out + (long)B_*S_*3;

    // ws layout (bytes) — audited (same as R12):
    //   0        scsh (10240) | 10240 pbE (reserve 327680) -> 337920
    //   337920   Wb(327680) -> 665600 | UW -> 681984 | VW -> 698368
    //   698368   idx(1MB) -> 1746944
    //   1746944  xTb(4MB) -> 5941248
    //   5941248  A2(2MB) -> 8038400
    //   8038400  pb1(2MB, ext1) THEN C2(2MB, ext2; disjoint lifetime) -> 10135552
    //   10135552 Cb(64MiB) -> 77244416
    //   77244416 X(64MiB) -> 144353280  (U = X+0 8MB, V2 = X+8MB; dead before X written)
    char* ws = (char*)d_ws;
    float*    scsh = (float*)(ws + 0);
    float*    pbE  = (float*)(ws + 10240);
    ushort_t* Wb   = (ushort_t*)(ws + 337920);
    ushort_t* UW   = (ushort_t*)(ws + 665600);
    ushort_t* VW   = (ushort_t*)(ws + 681984);
    int*      idx  = (int*)(ws + 698368);
    ushort_t* xTb  = (ushort_t*)(ws + 1746944);
    ushort_t* A2   = (ushort_t*)(ws + 5941248);
    float*    pb1  = (float*)(ws + 8038400);
    ushort_t* C2   = (ushort_t*)(ws + 8038400);
    ushort_t* Cb   = (ushort_t*)(ws + 10135552);
    ushort_t* X    = (ushort_t*)(ws + 77244416);
    ushort_t* U    = (ushort_t*)(ws + 77244416);
    ushort_t* V2   = (ushort_t*)(ws + 85633024);
    (void)in_sizes; (void)n_in; (void)out_size; (void)ws_size;

    const float inv1 = 1.0f/(float)NCOL1, inv2 = 1.0f/(float)NCOL2;
    const ushort_t* Wp = Wb;
    const ushort_t* Wq = Wb + 5*C_*C_;
    const int G1 = 2048;   // ext1: 4096 tiles of 64 cols, NT=2
    const int G2 = 64;     // ext2: 128 tiles of 64 cols, NT=2

    wcvt_kernel<<<704,256,0,stream>>>((const float*)d_in[3], (const float*)d_in[6],
                                      (const float*)d_in[9], (const float*)d_in[12], Wb, UW, VW);
    transpose_kernel<<<B_*(N_/64),256,0,stream>>>(x, xTb);
    knn_kernel<<<B_*S_,256,0,stream>>>(xyz, fps, idx, out_xyz);
    uv_gemm<<<320,256,0,stream>>>(xTb, fps, UW, VW, U, V2);

    // -------- extraction 1 --------
    {
        const float* G[5]  = {pre_bn_g, pre_bn_g+C_, pre_bn_g+2*C_, pre_bn_g+3*C_, pre_ffn_g};
        const float* Bv[5] = {pre_bn_b, pre_bn_b+C_, pre_bn_b+2*C_, pre_bn_b+3*C_, pre_ffn_b};
        gadd_kernel<<<2048,256,0,stream>>>(U, V2, idx, Cb, pb1, 2048);
        reduce_fin_kernel<<<128,256,0,stream>>>(pb1, scsh+0*256, G[0], Bv[0], inv1, 2048);
        conv_pipe<1,2><<<G1,256,0,stream>>>(Cb, nullptr, nullptr, Cb, Wp+1*C_*C_, scsh+0*256,
                                            nullptr, nullptr, nullptr, pb1, G1);
        reduce_fin_kernel<<<128,256,0,stream>>>(pb1, scsh+1*256, G[1], Bv[1], inv1, G1);
        conv_pipe<4,2><<<G1,256,0,stream>>>(Cb, nullptr, X, Cb, Wp+2*C_*C_, scsh+1*256,
                                            xTb, idx, fps, pb1, G1);
        reduce_fin_kernel<<<128,256,0,stream>>>(pb1, scsh+2*256, G[2], Bv[2], inv1, G1);
        conv_pipe<1,2><<<G1,256,0,stream>>>(Cb, nullptr, nullptr, Cb, Wp+3*C_*C_, scsh+2*256,
                                            nullptr, nullptr, nullptr, pb1, G1);
        reduce_fin_kernel<<<128,256,0,stream>>>(pb1, scsh+3*256, G[3], Bv[3], inv1, G1);
        conv_pipe<2,2><<<G1,256,0,stream>>>(Cb, X, X, Cb, Wp+4*C_*C_, scsh+3*256,
                                            nullptr, nullptr, nullptr, pb1, G1);
        reduce_fin_kernel<<<128,256,0,stream>>>(pb1, scsh+4*256, G[4], Bv[4], inv1, G1);
        pool_kernel<<<(NCOL2*64)/256,256,0,stream>>>(Cb, X, scsh+4*256, A2);
    }

    // -------- extraction 2: split launches, pipelined small convs --------
    {
        const float* G[5]  = {pos_bn_g, pos_bn_g+C_, pos_bn_g+2*C_, pos_bn_g+3*C_, pos_ffn_g};
        const float* Bv[5] = {pos_bn_b, pos_bn_b+C_, pos_bn_b+2*C_, pos_bn_b+3*C_, pos_ffn_b};
        conv_pipe<0,2><<<G2,256,0,stream>>>(A2, nullptr, nullptr, C2, Wq+0*C_*C_, nullptr,
                                            nullptr, nullptr, nullptr, pbE, G2);
        reduce_fin_kernel<<<128,256,0,stream>>>(pbE, scsh+5*256, G[0], Bv[0], inv2, G2);
        conv_pipe<1,2><<<G2,256,0,stream>>>(C2, nullptr, nullptr, C2, Wq+1*C_*C_, scsh+5*256,
                                            nullptr, nullptr, nullptr, pbE, G2);
        reduce_fin_kernel<<<128,256,0,stream>>>(pbE, scsh+6*256, G[1], Bv[1], inv2, G2);
        conv_pipe<2,2><<<G2,256,0,stream>>>(C2, A2, A2, C2, Wq+2*C_*C_, scsh+6*256,
                                            nullptr, nullptr, nullptr, pbE, G2);
        reduce_fin_kernel<<<128,256,0,stream>>>(pbE, scsh+7*256, G[2], Bv[2], inv2, G2);
        conv_pipe<1,2><<<G2,256,0,stream>>>(C2, nullptr, nullptr, C2, Wq+3*C_*C_, scsh+7*256,
                                            nullptr, nullptr, nullptr, pbE, G2);
        reduce_fin_kernel<<<128,256,0,stream>>>(pbE, scsh+8*256, G[3], Bv[3], inv2, G2);
        conv_pipe<2,2><<<G2,256,0,stream>>>(C2, A2, A2, C2, Wq+4*C_*C_, scsh+8*256,
                                            nullptr, nullptr, nullptr, pbE, G2);
        reduce_fin_kernel<<<128,256,0,stream>>>(pbE, scsh+9*256, G[4], Bv[4], inv2, G2);
        out2_kernel<<<64,256,0,stream>>>(C2, A2, scsh+9*256, out_y);
    }
}

// Round 14
// 643.538 us; speedup vs baseline: 1.1304x; 1.1304x over previous
//
#include <hip/hip_runtime.h>
#include <math.h>

typedef unsigned short ushort_t;
typedef unsigned long long u64;
typedef unsigned int uint32;

#define B_ 8
#define N_ 4096
#define S_ 1024
#define K_ 32
#define C_ 128
#define NCOL1 (B_*S_*K_)   // 262144
#define NCOL2 (B_*S_)      // 8192
#define EPS_ 1e-5f

typedef short s16x8 __attribute__((ext_vector_type(8)));
typedef float f32x4 __attribute__((ext_vector_type(4)));

__device__ __forceinline__ float bf2f(ushort_t u){ return __uint_as_float(((uint32)u)<<16); }
__device__ __forceinline__ ushort_t f2bf(float f){
    uint32 x = __float_as_uint(f);
    return (ushort_t)((x + 0x7FFFu + ((x>>16)&1u)) >> 16);
}
__device__ __forceinline__ float gelu_f(float v){
    float az = fabsf(v)*0.70710678118654752f;
    float t  = __builtin_amdgcn_rcpf(fmaf(0.3275911f, az, 1.0f));
    float p  = fmaf(fmaf(fmaf(fmaf(1.061405429f, t, -1.453152027f), t, 1.421413741f), t,
                   -0.284496736f), t, 0.254829592f)*t;
    float e  = __expf(-az*az);
    float er = fmaf(-p, e, 1.0f);
    float s  = (v < 0.0f) ? -er : er;
    return 0.5f*v*(1.0f+s);
}
__device__ __forceinline__ u64 shfl_xor_u64(u64 v, int m){
    int lo = __shfl_xor((int)(v & 0xFFFFFFFFull), m, 64);
    int hi = __shfl_xor((int)(v >> 32), m, 64);
    return (((u64)(uint32)hi) << 32) | (uint32)lo;
}
__device__ __forceinline__ void gl_lds16(const char* gp, char* lp){
    __builtin_amdgcn_global_load_lds((const __attribute__((address_space(1))) void*)gp,
                                     (__attribute__((address_space(3))) void*)lp, 16, 0, 0);
}

// ---------------- transpose x (B,64,N) -> xTb (B,N,64) bf16 ----------------
__global__ __launch_bounds__(256) void transpose_kernel(const float* __restrict__ x, ushort_t* __restrict__ xTb){
    __shared__ float t[64][65];
    int b  = blockIdx.x >> 6;
    int n0 = (blockIdx.x & 63) * 64;
    int tx = threadIdx.x & 63, ty = threadIdx.x >> 6;
    #pragma unroll
    for (int i=0;i<16;i++){
        int c = i*4 + ty;
        t[c][tx] = x[((long)(b*64 + c))*N_ + n0 + tx];
    }
    __syncthreads();
    #pragma unroll
    for (int i=0;i<16;i++){
        int n = i*4 + ty;
        xTb[((long)(b*N_ + n0 + n))*64 + tx] = f2bf(t[tx][n]);
    }
}

// ---------------- KNN: 2-level radix select (1024/4096 bins), exact ----------------
__global__ __launch_bounds__(256) void knn_kernel(const float* __restrict__ xyz, const int* __restrict__ fps,
                                                  int* __restrict__ idxg, float* __restrict__ newxyz){
    __shared__ uint32 hist[4096];
    __shared__ u64    cand[1024];
    __shared__ u64    out_keys[64];
    __shared__ uint32 csum[256];
    __shared__ uint32 wtot[4];
    __shared__ uint32 shv[8];
    __shared__ u64    wred[4];
    __shared__ u64    winner;

    int tid = threadIdx.x;
    int wv = tid >> 6, l = tid & 63;
    int bs = blockIdx.x;
    int b  = bs >> 10;
    int qi = fps[bs];
    const float* qb = xyz + ((long)b*N_ + qi)*3;
    float qx = qb[0], qy = qb[1], qz = qb[2];
    if (tid < 3) newxyz[(long)bs*3 + tid] = qb[tid];
    const float* xb = xyz + (long)b*N_*3;

    for (int i=tid;i<1024;i+=256) hist[i]=0;
    if (tid < 8) shv[tid]=0;
    __syncthreads();

    uint32 dbits[16];
    #pragma unroll
    for (int i=0;i<16;i++){
        int n = i*256 + tid;
        float dx = xb[n*3+0]-qx, dy = xb[n*3+1]-qy, dz = xb[n*3+2]-qz;
        float d = dx*dx + dy*dy + dz*dz;
        dbits[i] = __float_as_uint(d);
        atomicAdd(&hist[dbits[i]>>21], 1u);
    }
    __syncthreads();

    {
        uint32 h4[4]; uint32 csumv=0;
        #pragma unroll
        for (int i=0;i<4;i++){ h4[i]=hist[tid*4+i]; csumv+=h4[i]; }
        uint32 sc = csumv;
        #pragma unroll
        for (int off=1; off<64; off<<=1){ uint32 o=__shfl_up(sc,off,64); if (l>=off) sc+=o; }
        if (l==63) wtot[wv]=sc;
        csum[tid]=sc;
        __syncthreads();
        uint32 base=0;
        for (int w2=0; w2<wv; w2++) base += wtot[w2];
        uint32 cum = base + csum[tid] - csumv;
        #pragma unroll
        for (int i=0;i<4;i++){
            if (cum <= 31u && 31u < cum + h4[i]){ shv[0]=(uint32)(tid*4+i); shv[1]=cum; }
            cum += h4[i];
        }
    }
    __syncthreads();
    uint32 b1 = shv[0], cl1 = shv[1];

    for (int i=tid;i<4096;i+=256) hist[i]=0;
    __syncthreads();
    #pragma unroll
    for (int i=0;i<16;i++){
        uint32 u = dbits[i];
        if ((u>>21)==b1) atomicAdd(&hist[(u>>9)&0xFFFu], 1u);
    }
    __syncthreads();

    uint32 r2 = 31u - cl1;
    {
        uint32 h[16]; uint32 csumv=0;
        #pragma unroll
        for (int i=0;i<16;i++){ h[i]=hist[tid*16+i]; csumv += h[i]; }
        uint32 sc = csumv;
        #pragma unroll
        for (int off=1; off<64; off<<=1){ uint32 o=__shfl_up(sc,off,64); if (l>=off) sc+=o; }
        if (l==63) wtot[wv]=sc;
        csum[tid]=sc;
        __syncthreads();
        uint32 base=0;
        for (int w2=0; w2<wv; w2++) base += wtot[w2];
        uint32 cum = base + csum[tid] - csumv;
        #pragma unroll
        for (int i=0;i<16;i++){
            if (cum <= r2 && r2 < cum + h[i]){ shv[2]=(uint32)(tid*16+i); shv[3]=cum; }
            cum += h[i];
        }
    }
    __syncthreads();
    uint32 b2 = shv[2], cl2 = shv[3];
    uint32 nless = cl1 + cl2;

    #pragma unroll
    for (int i=0;i<16;i++){
        uint32 u = dbits[i];
        int n = i*256 + tid;
        uint32 bb1 = u >> 21;
        if (bb1 > b1) continue;
        u64 key = (((u64)u)<<32) | (uint32)n;
        if (bb1 < b1){
            uint32 p = atomicAdd(&shv[4],1u); out_keys[p] = key;
        } else {
            uint32 bb2 = (u>>9)&0xFFFu;
            if (bb2 < b2){ uint32 p = atomicAdd(&shv[4],1u); out_keys[p] = key; }
            else if (bb2 == b2){ uint32 p = atomicAdd(&shv[5],1u); if (p < 1024u) cand[p] = key; }
        }
    }
    __syncthreads();

    if (shv[5] > 1024u){
        uint32 alive = 0xFFFFu;
        for (int r=0;r<K_;r++){
            u64 lmin = ~0ull;
            #pragma unroll
            for (int i=0;i<16;i++){
                u64 k = (((u64)dbits[i])<<32) | (uint32)(i*256+tid);
                if (((alive>>i)&1u) && k < lmin) lmin = k;
            }
            #pragma unroll
            for (int off=32; off>=1; off>>=1){
                u64 o = shfl_xor_u64(lmin, off);
                if (o < lmin) lmin = o;
            }
            if (l == 0) wred[wv] = lmin;
            __syncthreads();
            if (tid == 0){
                u64 m = wred[0];
                if (wred[1]<m) m=wred[1];
                if (wred[2]<m) m=wred[2];
                if (wred[3]<m) m=wred[3];
                winner = m;
                idxg[(long)bs*K_ + r] = (int)(m & 0xFFFFFFFFull);
            }
            __syncthreads();
            u64 w = winner;
            #pragma unroll
            for (int i=0;i<16;i++){
                u64 k = (((u64)dbits[i])<<32) | (uint32)(i*256+tid);
                if (k == w) alive &= ~(1u<<i);
            }
        }
    } else if (wv == 0){
        uint32 cb   = shv[5];
        uint32 need = 32u - nless;
        for (uint32 r=0; r<need; r++){
            u64 lmin = ~0ull;
            for (uint32 s=l; s<cb; s+=64){ u64 kk = cand[s]; if (kk < lmin) lmin = kk; }
            #pragma unroll
            for (int off=32; off>=1; off>>=1){
                u64 o = shfl_xor_u64(lmin, off);
                if (o < lmin) lmin = o;
            }
            for (uint32 s=l; s<cb; s+=64){ if (cand[s]==lmin) cand[s] = ~0ull; }
            if (l==0) out_keys[nless + r] = lmin;
        }
        u64 key = (l < 32) ? out_keys[l] : ~0ull;
        #pragma unroll
        for (uint32 k=2; k<=64; k<<=1){
            bool dir = ((l & k)==0);
            #pragma unroll
            for (uint32 j=k>>1; j>=1; j>>=1){
                u64 o = shfl_xor_u64(key, j);
                bool lower = ((l & j)==0);
                u64 mn = (key < o) ? key : o;
                u64 mx = (key < o) ? o : key;
                key = (lower == dir) ? mn : mx;
            }
        }
        if (l < 32) idxg[(long)bs*K_ + l] = (int)(key & 0xFFFFFFFFull);
    }
}

// ---------------- weights f32 -> bf16 (10 mats) + UW/VW halves of W1 ----------------
__global__ __launch_bounds__(256) void wcvt_kernel(const float* __restrict__ pcw, const float* __restrict__ pfw,
                                                   const float* __restrict__ qcw, const float* __restrict__ qfw,
                                                   ushort_t* __restrict__ Wb, ushort_t* __restrict__ UW,
                                                   ushort_t* __restrict__ VW){
    int i = blockIdx.x*256 + threadIdx.x;   // 0 .. 180223
    if (i < 163840){
        int mat = i >> 14;
        int r = i & 16383;
        float v;
        if (mat < 4)       v = pcw[i];
        else if (mat == 4) v = pfw[r];
        else if (mat < 9)  v = qcw[i - 5*16384];
        else               v = qfw[r];
        Wb[i] = f2bf(v);
    } else {
        int j = i - 163840;                 // 0..16383
        int jj = j & 8191;
        int oc = jj >> 6, c = jj & 63;
        if (j < 8192) UW[jj] = f2bf(pcw[oc*128 + c]);
        else          VW[jj] = f2bf(pcw[oc*128 + 64 + c] - pcw[oc*128 + c]);
    }
}

// ---------------- U = xTb x UW^T ; V2[bs] = VW x xTb[fps[bs]] (K=64 GEMM) ----------------
__global__ __launch_bounds__(256) void uv_gemm(const ushort_t* __restrict__ xTb, const int* __restrict__ fps,
                                               const ushort_t* __restrict__ UW, const ushort_t* __restrict__ VW,
                                               ushort_t* __restrict__ U, ushort_t* __restrict__ V2){
    int tid = threadIdx.x;
    int w = tid >> 6, l = tid & 63;
    int l15 = l & 15, l4 = l >> 4;
    bool isV = blockIdx.x >= 256;
    int base = (isV ? (int)(blockIdx.x - 256) : (int)blockIdx.x)*128 + w*32;
    const ushort_t* Wh = isV ? VW : UW;
    ushort_t* out = isV ? V2 : U;

    long xrow[2];
    #pragma unroll
    for (int n=0;n<2;n++){
        int r = base + n*16 + l15;
        if (isV){ int b = r >> 10; xrow[n] = ((long)(b<<12) + fps[r]); }
        else    { xrow[n] = r; }
    }
    f32x4 acc[8][2] = {};
    #pragma unroll
    for (int ks=0; ks<2; ks++){
        int kl = ks*32 + l4*8;
        s16x8 af[8];
        #pragma unroll
        for (int m=0;m<8;m++)
            af[m] = *(const s16x8*)(Wh + (m*16 + l15)*64 + kl);
        s16x8 bv[2];
        #pragma unroll
        for (int n=0;n<2;n++)
            bv[n] = *(const s16x8*)(xTb + xrow[n]*64 + kl);
        #pragma unroll
        for (int m=0;m<8;m++)
            #pragma unroll
            for (int n=0;n<2;n++)
                acc[m][n] = __builtin_amdgcn_mfma_f32_16x16x32_bf16(af[m], bv[n], acc[m][n], 0, 0, 0);
    }
    #pragma unroll
    for (int n=0;n<2;n++){
        long radr = (long)(base + n*16 + l15)*C_;
        #pragma unroll
        for (int m=0;m<8;m++){
            f32x4 a = acc[m][n];
            uint2 st;
            st.x = (((uint32)f2bf(a[1]))<<16) | f2bf(a[0]);
            st.y = (((uint32)f2bf(a[3]))<<16) | f2bf(a[2]);
            *(uint2*)(out + radr + m*16 + l4*4) = st;
        }
    }
}

// ---------------- GADD: T1[col][oc] = U[idx[col]][oc] + V2[col>>5][oc], + BN stats ----------
__global__ __launch_bounds__(256) void gadd_kernel(const ushort_t* __restrict__ U, const ushort_t* __restrict__ V2,
                                                   const int* __restrict__ idxg, ushort_t* __restrict__ out,
                                                   float* __restrict__ pb, int nb){
    __shared__ float sL[4][128], qL[4][128];
    int tid = threadIdx.x;
    int w = tid >> 6, l = tid & 63;
    int l15 = l & 15, l4 = l >> 4;
    long col0 = ((long)blockIdx.x << 7) + ((long)w << 5);
    int bs = (int)(col0 >> 5);
    int b  = bs >> 10;
    const ushort_t* vrow = V2 + (long)bs*C_;

    f32x4 acc[8][2];
    #pragma unroll
    for (int n=0;n<2;n++){
        int nn = idxg[col0 + n*16 + l15];
        const ushort_t* urow = U + ((long)(b*4096) + nn)*C_;
        #pragma unroll
        for (int m=0;m<8;m++){
            int oc0 = m*16 + l4*4;
            uint2 uu = *(const uint2*)(urow + oc0);
            uint2 vv = *(const uint2*)(vrow + oc0);
            acc[m][n][0] = bf2f((ushort_t)(uu.x & 0xFFFFu)) + bf2f((ushort_t)(vv.x & 0xFFFFu));
            acc[m][n][1] = bf2f((ushort_t)(uu.x >> 16))     + bf2f((ushort_t)(vv.x >> 16));
            acc[m][n][2] = bf2f((ushort_t)(uu.y & 0xFFFFu)) + bf2f((ushort_t)(vv.y & 0xFFFFu));
            acc[m][n][3] = bf2f((ushort_t)(uu.y >> 16))     + bf2f((ushort_t)(vv.y >> 16));
        }
    }
    #pragma unroll
    for (int n=0;n<2;n++){
        long cadr = (col0 + n*16 + l15)*C_;
        #pragma unroll
        for (int m=0;m<8;m++){
            f32x4 a = acc[m][n];
            uint2 st;
            st.x = (((uint32)f2bf(a[1]))<<16) | f2bf(a[0]);
            st.y = (((uint32)f2bf(a[3]))<<16) | f2bf(a[2]);
            *(uint2*)(out + cadr + m*16 + l4*4) = st;
        }
    }
    #pragma unroll
    for (int m=0;m<8;m++){
        #pragma unroll
        for (int r=0;r<4;r++){
            float a0=acc[m][0][r], a1=acc[m][1][r];
            float s = a0+a1;
            float q = a0*a0+a1*a1;
            #pragma unroll
            for (int off=1; off<16; off<<=1){
                s += __shfl_xor(s, off, 64);
                q += __shfl_xor(q, off, 64);
            }
            if (l15 == 0){
                sL[w][m*16 + l4*4 + r] = s;
                qL[w][m*16 + l4*4 + r] = q;
            }
        }
    }
    __syncthreads();
    if (tid < 128){
        float s = sL[0][tid] + sL[1][tid] + sL[2][tid] + sL[3][tid];
        float q = qL[0][tid] + qL[1][tid] + qL[2][tid] + qL[3][tid];
        pb[(long)tid*nb + blockIdx.x]       = s;
        pb[(long)(128+tid)*nb + blockIdx.x] = q;
    }
}

// ---------------- conv: W in LDS (swizzled), input streamed via registers ----------------
// 64-col tiles, NT per block; wave w owns cols [tile*64+w*16, +16). Input for tile t+1
// prefetched into regs (pinned cluster) before compute of t; compiler inserts counted
// waits at first use -> loads stay in flight across the whole compute phase. W fragments
// read from LDS (conflict-free XOR swizzle) - removes the per-ks global W latency chain.
// MODE: 0 RAW | 1 PRE gelu(bn(in1)) | 2 RESID gelu(bn(in1)+in2), aux-store
//       4 RESID_VIRT (feature gather from xTb/idx/fps; idx/fps resolved in prologue), aux-store
template<int MODE, int NT>
__global__ __launch_bounds__(256, 3) void conv_pipe(const ushort_t* in1, const ushort_t* in2, ushort_t* aux,
        ushort_t* out, const ushort_t* __restrict__ Wg, const float* __restrict__ scsh_g,
        const ushort_t* __restrict__ xTb, const int* __restrict__ idxg, const int* __restrict__ fps,
        float* __restrict__ pb, int nb){
    __shared__ ushort_t WL[16384];       // 32 KB weight matrix (swizzled layout)
    __shared__ float ss[256];
    __shared__ float sL[4][128], qL[4][128];
    int tid = threadIdx.x;
    int w = tid >> 6, l = tid & 63;
    int l15 = l & 15, l4 = l >> 4;
    int G = gridDim.x;

    // stage W once per block: pre-swizzled source, linear LDS dest (m173 pattern)
    {
        const char* gw = (const char*)Wg;
        #pragma unroll
        for (int i=0;i<2;i++){
            int p = i*4096 + tid*16;
            int src = p ^ (((p>>8)&7)<<4);
            gl_lds16(gw + src, (char*)WL + p);
        }
        #pragma unroll
        for (int i=2;i<8;i++){
            int p = i*4096 + tid*16;
            int src = p ^ (((p>>8)&7)<<4);
            gl_lds16(gw + src, (char*)WL + p);
        }
    }
    sL[w][l] = 0.f; sL[w][64+l] = 0.f;
    qL[w][l] = 0.f; qL[w][64+l] = 0.f;
    if (MODE != 0) ss[tid] = scsh_g[tid];

    // MODE4 prologue: resolve idx/fps for all tiles (kills dependent-load stalls later)
    int idxv[NT]; int fpsv[NT];
    if (MODE == 4){
        #pragma unroll
        for (int t=0;t<NT;t++){
            long c0 = (((long)t*G + blockIdx.x) << 6) + (w<<4);
            idxv[t] = idxg[c0 + l15];
            fpsv[t] = fps[(int)(c0>>5)];
        }
    }

    // tile-0 input (+resid) into registers
    s16x8 vin[2][4];
    s16x8 a2[2][4];
    {
        long c0 = ((long)blockIdx.x << 6) + (w<<4);
        const ushort_t* ip = in1 + (c0 + l15)*C_;
        #pragma unroll
        for (int ks=0;ks<4;ks++) vin[0][ks] = *(const s16x8*)(ip + ks*32 + l4*8);
        if (MODE == 2){
            const ushort_t* ap = in2 + (c0 + l15)*C_;
            #pragma unroll
            for (int ks=0;ks<4;ks++) a2[0][ks] = *(const s16x8*)(ap + ks*32 + l4*8);
        }
    }
    __syncthreads();   // WL visible (drains gl_lds)

    #pragma unroll
    for (int t=0; t<NT; t++){
        long tile = (long)t*G + blockIdx.x;
        long col0 = (tile << 6) + (w<<4);

        // ---- pinned prefetch of tile t+1 into the other reg set ----
        if (t+1 < NT){
            __builtin_amdgcn_sched_barrier(0);
            long c1 = ((tile + G) << 6) + (w<<4);
            const ushort_t* ip = in1 + (c1 + l15)*C_;
            #pragma unroll
            for (int ks=0;ks<4;ks++) vin[(t+1)&1][ks] = *(const s16x8*)(ip + ks*32 + l4*8);
            if (MODE == 2){
                const ushort_t* ap = in2 + (c1 + l15)*C_;
                #pragma unroll
                for (int ks=0;ks<4;ks++) a2[(t+1)&1][ks] = *(const s16x8*)(ap + ks*32 + l4*8);
            }
            __builtin_amdgcn_sched_barrier(0);
        }

        // MODE4: gather residual feature rows for tile t (L2/L3-hot; idx pre-resolved)
        if (MODE == 4){
            int bs = (int)(col0 >> 5);
            int b  = bs >> 10;
            const ushort_t* crow = xTb + ((long)(b<<12) + fpsv[t])*64;
            s16x8 cv0 = *(const s16x8*)(crow + l4*8);
            s16x8 cv1 = *(const s16x8*)(crow + 32 + l4*8);
            const ushort_t* prow = xTb + ((long)(b<<12) + idxv[t])*64;
            s16x8 p0 = *(const s16x8*)(prow + l4*8);
            s16x8 p1 = *(const s16x8*)(prow + 32 + l4*8);
            s16x8 d0, d1;
            #pragma unroll
            for (int e=0;e<8;e++){
                d0[e] = (short)f2bf(bf2f((ushort_t)p0[e]) - bf2f((ushort_t)cv0[e]));
                d1[e] = (short)f2bf(bf2f((ushort_t)p1[e]) - bf2f((ushort_t)cv1[e]));
            }
            a2[t&1][0]=d0; a2[t&1][1]=d1; a2[t&1][2]=cv0; a2[t&1][3]=cv1;
        }

        // ---- compute tile t: W from LDS, input from regs ----
        f32x4 acc[8] = {};
        #pragma unroll
        for (int ks=0; ks<4; ks++){
            int kl = ks*32 + l4*8;
            s16x8 af[8];
            #pragma unroll
            for (int m=0;m<8;m++){
                int q  = (m*16 + l15)*256 + ks*64 + l4*16;
                int qs = q ^ (((q>>8)&7)<<4);
                af[m] = *(const s16x8*)((const char*)WL + qs);
            }
            s16x8 v = vin[t&1][ks];
            if (MODE != 0){
                float sc[8], sh[8];
                const float4* sp = (const float4*)(&ss[kl*2]);
                float4 s0 = sp[0], s1 = sp[1], s2 = sp[2], s3 = sp[3];
                sc[0]=s0.x; sh[0]=s0.y; sc[1]=s0.z; sh[1]=s0.w;
                sc[2]=s1.x; sh[2]=s1.y; sc[3]=s1.z; sh[3]=s1.w;
                sc[4]=s2.x; sh[4]=s2.y; sc[5]=s2.z; sh[5]=s2.w;
                sc[6]=s3.x; sh[6]=s3.y; sc[7]=s3.z; sh[7]=s3.w;
                if (MODE == 1){
                    #pragma unroll
                    for (int e=0;e<8;e++){
                        float f = gelu_f(fmaf(bf2f((ushort_t)v[e]), sc[e], sh[e]));
                        v[e] = (short)f2bf(f);
                    }
                } else {
                    s16x8 a = a2[t&1][ks];
                    #pragma unroll
                    for (int e=0;e<8;e++){
                        float f = gelu_f(fmaf(bf2f((ushort_t)v[e]), sc[e], sh[e]) + bf2f((ushort_t)a[e]));
                        v[e] = (short)f2bf(f);
                    }
                }
                if (MODE == 2 || MODE == 4)
                    *(s16x8*)(aux + (col0 + l15)*C_ + kl) = v;     // wave-private col
            }
            #pragma unroll
            for (int m=0;m<8;m++)
                acc[m] = __builtin_amdgcn_mfma_f32_16x16x32_bf16(af[m], v, acc[m], 0, 0, 0);
        }

        // ---- out stores (wave-private 16-col region) ----
        {
            long cadr = (col0 + l15)*C_;
            #pragma unroll
            for (int m=0;m<8;m++){
                f32x4 a = acc[m];
                uint2 st;
                st.x = (((uint32)f2bf(a[1]))<<16) | f2bf(a[0]);
                st.y = (((uint32)f2bf(a[3]))<<16) | f2bf(a[2]);
                *(uint2*)(out + cadr + m*16 + l4*4) = st;
            }
        }

        // ---- BN stats accumulate (wave-private LDS rows) ----
        #pragma unroll
        for (int m=0;m<8;m++){
            #pragma unroll
            for (int r=0;r<4;r++){
                float s = acc[m][r];
                float q = s*s;
                #pragma unroll
                for (int off=1; off<16; off<<=1){
                    s += __shfl_xor(s, off, 64);
                    q += __shfl_xor(q, off, 64);
                }
                if (l15 == 0){
                    sL[w][m*16 + l4*4 + r] += s;
                    qL[w][m*16 + l4*4 + r] += q;
                }
            }
        }
    }

    __syncthreads();
    if (tid < 128){
        float s = sL[0][tid] + sL[1][tid] + sL[2][tid] + sL[3][tid];
        float q = qL[0][tid] + qL[1][tid] + qL[2][tid] + qL[3][tid];
        pb[(long)tid*nb + blockIdx.x]       = s;
        pb[(long)(128+tid)*nb + blockIdx.x] = q;
    }
}

// ---------------- reduce partials[256][nb] -> (scale, shift) ----------------
__global__ __launch_bounds__(256) void reduce_fin_kernel(const float* __restrict__ pb, float* __restrict__ scsh,
                                                         const float* __restrict__ g, const float* __restrict__ bb,
                                                         float inv_cnt, int nb){
    int oc = blockIdx.x;
    float s=0.f, q=0.f;
    for (int b=threadIdx.x; b<nb; b+=256){
        s += pb[(long)oc*nb + b];
        q += pb[(long)(128+oc)*nb + b];
    }
    __shared__ float ls[256], lq[256];
    ls[threadIdx.x]=s; lq[threadIdx.x]=q;
    __syncthreads();
    #pragma unroll
    for (int st_=128; st_>0; st_>>=1){
        if (threadIdx.x < st_){ ls[threadIdx.x]+=ls[threadIdx.x+st_]; lq[threadIdx.x]+=lq[threadIdx.x+st_]; }
        __syncthreads();
    }
    if (threadIdx.x==0){
        float mean = ls[0]*inv_cnt;
        float var  = lq[0]*inv_cnt - mean*mean;
        float sc   = g[oc]*rsqrtf(var + EPS_);
        scsh[oc*2+0] = sc;
        scsh[oc*2+1] = bb[oc] - mean*sc;
    }
}

// ---------------- pool with fused resid: A2[bs][c] = max_k gelu(bn(T)+X) ----------------
__global__ __launch_bounds__(256) void pool_kernel(const ushort_t* __restrict__ T, const ushort_t* __restrict__ X,
                                                   const float* __restrict__ scsh, ushort_t* __restrict__ A2){
    long p  = (long)blockIdx.x*256 + threadIdx.x;
    long bs = p >> 6;
    int  c0 = ((int)p & 63)*2;
    float sc0=scsh[c0*2], sh0=scsh[c0*2+1], sc1=scsh[c0*2+2], sh1=scsh[c0*2+3];
    const ushort_t* tb = T + (bs*K_)*(long)C_ + c0;
    const ushort_t* xv = X + (bs*K_)*(long)C_ + c0;
    float m0 = -1e30f, m1 = -1e30f;
    #pragma unroll 4
    for (int k=0;k<K_;k++){
        uint32 tv = *(const uint32*)(tb + (long)k*C_);
        uint32 av = *(const uint32*)(xv + (long)k*C_);
        float v0 = gelu_f(fmaf(bf2f((ushort_t)(tv & 0xFFFFu)), sc0, sh0) + bf2f((ushort_t)(av & 0xFFFFu)));
        float v1 = gelu_f(fmaf(bf2f((ushort_t)(tv >> 16)),     sc1, sh1) + bf2f((ushort_t)(av >> 16)));
        m0 = fmaxf(m0, v0);
        m1 = fmaxf(m1, v1);
    }
    uint32 o = (((uint32)f2bf(m1))<<16) | f2bf(m0);
    *(uint32*)(A2 + bs*C_ + c0) = o;
}

// ---------------- out2: y[b][c][s] = gelu(bn(T)+X), LDS-tiled, coalesced ----------------
__global__ __launch_bounds__(256) void out2_kernel(const ushort_t* __restrict__ T, const ushort_t* __restrict__ X,
                                                   const float* __restrict__ scsh_g, float* __restrict__ y){
    __shared__ ushort_t Ts[16384];
    __shared__ ushort_t Xs[16384];
    __shared__ float ss[256];
    int tid = threadIdx.x, w = tid>>6, l = tid&63;
    int blk = blockIdx.x;

    {
        const char* gt = (const char*)(T + ((long)blk << 7)*C_);
        const char* gx = (const char*)(X + ((long)blk << 7)*C_);
        #pragma unroll
        for (int i=0;i<8;i++){
            int p = i*4096 + w*1024 + l*16;
            int src = p ^ (((p>>8)&7)<<4);
            gl_lds16(gt + src, (char*)Ts + i*4096 + w*1024);
            gl_lds16(gx + src, (char*)Xs + i*4096 + w*1024);
        }
    }
    ss[tid] = scsh_g[tid];
    __syncthreads();

    int b  = blk >> 3;
    int s0 = (blk & 7) * 128;
    int colL = tid & 127;
    int rep  = tid >> 7;
    #pragma unroll
    for (int cb=0; cb<8; cb++){
        int q  = colL*256 + rep*128 + cb*16;
        int qs = q ^ (((q>>8)&7)<<4);
        s16x8 tvv = *(const s16x8*)((char*)Ts + qs);
        s16x8 xvv = *(const s16x8*)((char*)Xs + qs);
        #pragma unroll
        for (int e=0;e<8;e++){
            int c = rep*64 + cb*8 + e;
            float f = gelu_f(fmaf(bf2f((ushort_t)tvv[e]), ss[c*2], ss[c*2+1]) + bf2f((ushort_t)xvv[e]));
            y[((long)(b*C_ + c))*S_ + s0 + colL] = f;
        }
    }
}

// ---------------- host ----------------
extern "C" void kernel_launch(void* const* d_in, const int* in_sizes, int n_in,
                              void* d_out, int out_size, void* d_ws, size_t ws_size,
                              hipStream_t stream){
    const float* xyz        = (const float*)d_in[0];
    const float* x          = (const float*)d_in[1];
    const int*   fps        = (const int*)d_in[2];
    const float* pre_bn_g   = (const float*)d_in[4];
    const float* pre_bn_b   = (const float*)d_in[5];
    const float* pre_ffn_g  = (const float*)d_in[7];
    const float* pre_ffn_b  = (const float*)d_in[8];
    const float* pos_bn_g   = (const float*)d_in[10];
    const float* pos_bn_b   = (const float*)d_in[11];
    const float* pos_ffn_g  = (const float*)d_in[13];
    const float* pos_ffn_b  = (const float*)d_in[14];

    float* out_xyz = (float*)d_out;
    float* out_y   = (float*)d_out + (long)B_*S_*3;

    // ws layout (bytes) — audited (same as R12/R13):
    //   0        scsh (10240) | 10240 pbE (reserve 327680) -> 337920
    //   337920   Wb(327680) -> 665600 | UW -> 681984 | VW -> 698368
    //   698368   idx(1MB) -> 1746944
    //   1746944  xTb(4MB) -> 5941248
    //   5941248  A2(2MB) -> 8038400
    //   8038400  pb1(2MB, ext1) THEN C2(2MB, ext2; disjoint lifetime) -> 10135552
    //   10135552 Cb(64MiB) -> 77244416
    //   77244416 X(64MiB) -> 144353280  (U = X+0 8MB, V2 = X+8MB; dead before X written)
    char* ws = (char*)d_ws;
    float*    scsh = (float*)(ws + 0);
    float*    pbE  = (float*)(ws + 10240);
    ushort_t* Wb   = (ushort_t*)(ws + 337920);
    ushort_t* UW   = (ushort_t*)(ws + 665600);
    ushort_t* VW   = (ushort_t*)(ws + 681984);
    int*      idx  = (int*)(ws + 698368);
    ushort_t* xTb  = (ushort_t*)(ws + 1746944);
    ushort_t* A2   = (ushort_t*)(ws + 5941248);
    float*    pb1  = (float*)(ws + 8038400);
    ushort_t* C2   = (ushort_t*)(ws + 8038400);
    ushort_t* Cb   = (ushort_t*)(ws + 10135552);
    ushort_t* X    = (ushort_t*)(ws + 77244416);
    ushort_t* U    = (ushort_t*)(ws + 77244416);
    ushort_t* V2   = (ushort_t*)(ws + 85633024);
    (void)in_sizes; (void)n_in; (void)out_size; (void)ws_size;

    const float inv1 = 1.0f/(float)NCOL1, inv2 = 1.0f/(float)NCOL2;
    const ushort_t* Wp = Wb;
    const ushort_t* Wq = Wb + 5*C_*C_;
    const int G1 = 1024;   // ext1: 4096 tiles of 64 cols, NT=4
    const int G2 = 64;     // ext2: 128 tiles of 64 cols, NT=2

    wcvt_kernel<<<704,256,0,stream>>>((const float*)d_in[3], (const float*)d_in[6],
                                      (const float*)d_in[9], (const float*)d_in[12], Wb, UW, VW);
    transpose_kernel<<<B_*(N_/64),256,0,stream>>>(x, xTb);
    knn_kernel<<<B_*S_,256,0,stream>>>(xyz, fps, idx, out_xyz);
    uv_gemm<<<320,256,0,stream>>>(xTb, fps, UW, VW, U, V2);

    // -------- extraction 1 --------
    {
        const float* G[5]  = {pre_bn_g, pre_bn_g+C_, pre_bn_g+2*C_, pre_bn_g+3*C_, pre_ffn_g};
        const float* Bv[5] = {pre_bn_b, pre_bn_b+C_, pre_bn_b+2*C_, pre_bn_b+3*C_, pre_ffn_b};
        gadd_kernel<<<2048,256,0,stream>>>(U, V2, idx, Cb, pb1, 2048);
        reduce_fin_kernel<<<128,256,0,stream>>>(pb1, scsh+0*256, G[0], Bv[0], inv1, 2048);
        conv_pipe<1,4><<<G1,256,0,stream>>>(Cb, nullptr, nullptr, Cb, Wp+1*C_*C_, scsh+0*256,
                                            nullptr, nullptr, nullptr, pb1, G1);
        reduce_fin_kernel<<<128,256,0,stream>>>(pb1, scsh+1*256, G[1], Bv[1], inv1, G1);
        conv_pipe<4,4><<<G1,256,0,stream>>>(Cb, nullptr, X, Cb, Wp+2*C_*C_, scsh+1*256,
                                            xTb, idx, fps, pb1, G1);
        reduce_fin_kernel<<<128,256,0,stream>>>(pb1, scsh+2*256, G[2], Bv[2], inv1, G1);
        conv_pipe<1,4><<<G1,256,0,stream>>>(Cb, nullptr, nullptr, Cb, Wp+3*C_*C_, scsh+2*256,
                                            nullptr, nullptr, nullptr, pb1, G1);
        reduce_fin_kernel<<<128,256,0,stream>>>(pb1, scsh+3*256, G[3], Bv[3], inv1, G1);
        conv_pipe<2,4><<<G1,256,0,stream>>>(Cb, X, X, Cb, Wp+4*C_*C_, scsh+3*256,
                                            nullptr, nullptr, nullptr, pb1, G1);
        reduce_fin_kernel<<<128,256,0,stream>>>(pb1, scsh+4*256, G[4], Bv[4], inv1, G1);
        pool_kernel<<<(NCOL2*64)/256,256,0,stream>>>(Cb, X, scsh+4*256, A2);
    }

    // -------- extraction 2: split launches --------
    {
        const float* G[5]  = {pos_bn_g, pos_bn_g+C_, pos_bn_g+2*C_, pos_bn_g+3*C_, pos_ffn_g};
        const float* Bv[5] = {pos_bn_b, pos_bn_b+C_, pos_bn_b+2*C_, pos_bn_b+3*C_, pos_ffn_b};
        conv_pipe<0,2><<<G2,256,0,stream>>>(A2, nullptr, nullptr, C2, Wq+0*C_*C_, nullptr,
                                            nullptr, nullptr, nullptr, pbE, G2);
        reduce_fin_kernel<<<128,256,0,stream>>>(pbE, scsh+5*256, G[0], Bv[0], inv2, G2);
        conv_pipe<1,2><<<G2,256,0,stream>>>(C2, nullptr, nullptr, C2, Wq+1*C_*C_, scsh+5*256,
                                            nullptr, nullptr, nullptr, pbE, G2);
        reduce_fin_kernel<<<128,256,0,stream>>>(pbE, scsh+6*256, G[1], Bv[1], inv2, G2);
        conv_pipe<2,2><<<G2,256,0,stream>>>(C2, A2, A2, C2, Wq+2*C_*C_, scsh+6*256,
                                            nullptr, nullptr, nullptr, pbE, G2);
        reduce_fin_kernel<<<128,256,0,stream>>>(pbE, scsh+7*256, G[2], Bv[2], inv2, G2);
        conv_pipe<1,2><<<G2,256,0,stream>>>(C2, nullptr, nullptr, C2, Wq+3*C_*C_, scsh+7*256,
                                            nullptr, nullptr, nullptr, pbE, G2);
        reduce_fin_kernel<<<128,256,0,stream>>>(pbE, scsh+8*256, G[3], Bv[3], inv2, G2);
        conv_pipe<2,2><<<G2,256,0,stream>>>(C2, A2, A2, C2, Wq+4*C_*C_, scsh+8*256,
                                            nullptr, nullptr, nullptr, pbE, G2);
        reduce_fin_kernel<<<128,256,0,stream>>>(pbE, scsh+9*256, G[4], Bv[4], inv2, G2);
        out2_kernel<<<64,256,0,stream>>>(C2, A2, scsh+9*256, out_y);
    }
}

// Round 15
// 590.011 us; speedup vs baseline: 1.2329x; 1.0907x over previous
//
#include <hip/hip_runtime.h>
#include <math.h>

typedef unsigned short ushort_t;
typedef unsigned long long u64;
typedef unsigned int uint32;

#define B_ 8
#define N_ 4096
#define S_ 1024
#define K_ 32
#define C_ 128
#define NCOL1 (B_*S_*K_)   // 262144
#define NCOL2 (B_*S_)      // 8192
#define EPS_ 1e-5f

typedef short s16x8 __attribute__((ext_vector_type(8)));
typedef float f32x4 __attribute__((ext_vector_type(4)));

__device__ __forceinline__ float bf2f(ushort_t u){ return __uint_as_float(((uint32)u)<<16); }
__device__ __forceinline__ ushort_t f2bf(float f){
    uint32 x = __float_as_uint(f);
    return (ushort_t)((x + 0x7FFFu + ((x>>16)&1u)) >> 16);
}
__device__ __forceinline__ float gelu_f(float v){
    float az = fabsf(v)*0.70710678118654752f;
    float t  = __builtin_amdgcn_rcpf(fmaf(0.3275911f, az, 1.0f));
    float p  = fmaf(fmaf(fmaf(fmaf(1.061405429f, t, -1.453152027f), t, 1.421413741f), t,
                   -0.284496736f), t, 0.254829592f)*t;
    float e  = __expf(-az*az);
    float er = fmaf(-p, e, 1.0f);
    float s  = (v < 0.0f) ? -er : er;
    return 0.5f*v*(1.0f+s);
}
__device__ __forceinline__ u64 shfl_xor_u64(u64 v, int m){
    int lo = __shfl_xor((int)(v & 0xFFFFFFFFull), m, 64);
    int hi = __shfl_xor((int)(v >> 32), m, 64);
    return (((u64)(uint32)hi) << 32) | (uint32)lo;
}
__device__ __forceinline__ void gl_lds16(const char* gp, char* lp){
    __builtin_amdgcn_global_load_lds((const __attribute__((address_space(1))) void*)gp,
                                     (__attribute__((address_space(3))) void*)lp, 16, 0, 0);
}

// ---------------- transpose x (B,64,N) -> xTb (B,N,64) bf16 ----------------
__global__ __launch_bounds__(256) void transpose_kernel(const float* __restrict__ x, ushort_t* __restrict__ xTb){
    __shared__ float t[64][65];
    int b  = blockIdx.x >> 6;
    int n0 = (blockIdx.x & 63) * 64;
    int tx = threadIdx.x & 63, ty = threadIdx.x >> 6;
    #pragma unroll
    for (int i=0;i<16;i++){
        int c = i*4 + ty;
        t[c][tx] = x[((long)(b*64 + c))*N_ + n0 + tx];
    }
    __syncthreads();
    #pragma unroll
    for (int i=0;i<16;i++){
        int n = i*4 + ty;
        xTb[((long)(b*N_ + n0 + n))*64 + tx] = f2bf(t[tx][n]);
    }
}

// ---------------- KNN: 2-level radix select (1024/4096 bins), exact ----------------
__global__ __launch_bounds__(256) void knn_kernel(const float* __restrict__ xyz, const int* __restrict__ fps,
                                                  int* __restrict__ idxg, float* __restrict__ newxyz){
    __shared__ uint32 hist[4096];
    __shared__ u64    cand[1024];
    __shared__ u64    out_keys[64];
    __shared__ uint32 csum[256];
    __shared__ uint32 wtot[4];
    __shared__ uint32 shv[8];
    __shared__ u64    wred[4];
    __shared__ u64    winner;

    int tid = threadIdx.x;
    int wv = tid >> 6, l = tid & 63;
    int bs = blockIdx.x;
    int b  = bs >> 10;
    int qi = fps[bs];
    const float* qb = xyz + ((long)b*N_ + qi)*3;
    float qx = qb[0], qy = qb[1], qz = qb[2];
    if (tid < 3) newxyz[(long)bs*3 + tid] = qb[tid];
    const float* xb = xyz + (long)b*N_*3;

    for (int i=tid;i<1024;i+=256) hist[i]=0;
    if (tid < 8) shv[tid]=0;
    __syncthreads();

    uint32 dbits[16];
    #pragma unroll
    for (int i=0;i<16;i++){
        int n = i*256 + tid;
        float dx = xb[n*3+0]-qx, dy = xb[n*3+1]-qy, dz = xb[n*3+2]-qz;
        float d = dx*dx + dy*dy + dz*dz;
        dbits[i] = __float_as_uint(d);
        atomicAdd(&hist[dbits[i]>>21], 1u);
    }
    __syncthreads();

    {
        uint32 h4[4]; uint32 csumv=0;
        #pragma unroll
        for (int i=0;i<4;i++){ h4[i]=hist[tid*4+i]; csumv+=h4[i]; }
        uint32 sc = csumv;
        #pragma unroll
        for (int off=1; off<64; off<<=1){ uint32 o=__shfl_up(sc,off,64); if (l>=off) sc+=o; }
        if (l==63) wtot[wv]=sc;
        csum[tid]=sc;
        __syncthreads();
        uint32 base=0;
        for (int w2=0; w2<wv; w2++) base += wtot[w2];
        uint32 cum = base + csum[tid] - csumv;
        #pragma unroll
        for (int i=0;i<4;i++){
            if (cum <= 31u && 31u < cum + h4[i]){ shv[0]=(uint32)(tid*4+i); shv[1]=cum; }
            cum += h4[i];
        }
    }
    __syncthreads();
    uint32 b1 = shv[0], cl1 = shv[1];

    for (int i=tid;i<4096;i+=256) hist[i]=0;
    __syncthreads();
    #pragma unroll
    for (int i=0;i<16;i++){
        uint32 u = dbits[i];
        if ((u>>21)==b1) atomicAdd(&hist[(u>>9)&0xFFFu], 1u);
    }
    __syncthreads();

    uint32 r2 = 31u - cl1;
    {
        uint32 h[16]; uint32 csumv=0;
        #pragma unroll
        for (int i=0;i<16;i++){ h[i]=hist[tid*16+i]; csumv += h[i]; }
        uint32 sc = csumv;
        #pragma unroll
        for (int off=1; off<64; off<<=1){ uint32 o=__shfl_up(sc,off,64); if (l>=off) sc+=o; }
        if (l==63) wtot[wv]=sc;
        csum[tid]=sc;
        __syncthreads();
        uint32 base=0;
        for (int w2=0; w2<wv; w2++) base += wtot[w2];
        uint32 cum = base + csum[tid] - csumv;
        #pragma unroll
        for (int i=0;i<16;i++){
            if (cum <= r2 && r2 < cum + h[i]){ shv[2]=(uint32)(tid*16+i); shv[3]=cum; }
            cum += h[i];
        }
    }
    __syncthreads();
    uint32 b2 = shv[2], cl2 = shv[3];
    uint32 nless = cl1 + cl2;

    #pragma unroll
    for (int i=0;i<16;i++){
        uint32 u = dbits[i];
        int n = i*256 + tid;
        uint32 bb1 = u >> 21;
        if (bb1 > b1) continue;
        u64 key = (((u64)u)<<32) | (uint32)n;
        if (bb1 < b1){
            uint32 p = atomicAdd(&shv[4],1u); out_keys[p] = key;
        } else {
            uint32 bb2 = (u>>9)&0xFFFu;
            if (bb2 < b2){ uint32 p = atomicAdd(&shv[4],1u); out_keys[p] = key; }
            else if (bb2 == b2){ uint32 p = atomicAdd(&shv[5],1u); if (p < 1024u) cand[p] = key; }
        }
    }
    __syncthreads();

    if (shv[5] > 1024u){
        uint32 alive = 0xFFFFu;
        for (int r=0;r<K_;r++){
            u64 lmin = ~0ull;
            #pragma unroll
            for (int i=0;i<16;i++){
                u64 k = (((u64)dbits[i])<<32) | (uint32)(i*256+tid);
                if (((alive>>i)&1u) && k < lmin) lmin = k;
            }
            #pragma unroll
            for (int off=32; off>=1; off>>=1){
                u64 o = shfl_xor_u64(lmin, off);
                if (o < lmin) lmin = o;
            }
            if (l == 0) wred[wv] = lmin;
            __syncthreads();
            if (tid == 0){
                u64 m = wred[0];
                if (wred[1]<m) m=wred[1];
                if (wred[2]<m) m=wred[2];
                if (wred[3]<m) m=wred[3];
                winner = m;
                idxg[(long)bs*K_ + r] = (int)(m & 0xFFFFFFFFull);
            }
            __syncthreads();
            u64 w = winner;
            #pragma unroll
            for (int i=0;i<16;i++){
                u64 k = (((u64)dbits[i])<<32) | (uint32)(i*256+tid);
                if (k == w) alive &= ~(1u<<i);
            }
        }
    } else if (wv == 0){
        uint32 cb   = shv[5];
        uint32 need = 32u - nless;
        for (uint32 r=0; r<need; r++){
            u64 lmin = ~0ull;
            for (uint32 s=l; s<cb; s+=64){ u64 kk = cand[s]; if (kk < lmin) lmin = kk; }
            #pragma unroll
            for (int off=32; off>=1; off>>=1){
                u64 o = shfl_xor_u64(lmin, off);
                if (o < lmin) lmin = o;
            }
            for (uint32 s=l; s<cb; s+=64){ if (cand[s]==lmin) cand[s] = ~0ull; }
            if (l==0) out_keys[nless + r] = lmin;
        }
        u64 key = (l < 32) ? out_keys[l] : ~0ull;
        #pragma unroll
        for (uint32 k=2; k<=64; k<<=1){
            bool dir = ((l & k)==0);
            #pragma unroll
            for (uint32 j=k>>1; j>=1; j>>=1){
                u64 o = shfl_xor_u64(key, j);
                bool lower = ((l & j)==0);
                u64 mn = (key < o) ? key : o;
                u64 mx = (key < o) ? o : key;
                key = (lower == dir) ? mn : mx;
            }
        }
        if (l < 32) idxg[(long)bs*K_ + l] = (int)(key & 0xFFFFFFFFull);
    }
}

// ---------------- weights f32 -> bf16 (10 mats) + UW/VW halves of W1 ----------------
__global__ __launch_bounds__(256) void wcvt_kernel(const float* __restrict__ pcw, const float* __restrict__ pfw,
                                                   const float* __restrict__ qcw, const float* __restrict__ qfw,
                                                   ushort_t* __restrict__ Wb, ushort_t* __restrict__ UW,
                                                   ushort_t* __restrict__ VW){
    int i = blockIdx.x*256 + threadIdx.x;   // 0 .. 180223
    if (i < 163840){
        int mat = i >> 14;
        int r = i & 16383;
        float v;
        if (mat < 4)       v = pcw[i];
        else if (mat == 4) v = pfw[r];
        else if (mat < 9)  v = qcw[i - 5*16384];
        else               v = qfw[r];
        Wb[i] = f2bf(v);
    } else {
        int j = i - 163840;                 // 0..16383
        int jj = j & 8191;
        int oc = jj >> 6, c = jj & 63;
        if (j < 8192) UW[jj] = f2bf(pcw[oc*128 + c]);
        else          VW[jj] = f2bf(pcw[oc*128 + 64 + c] - pcw[oc*128 + c]);
    }
}

// ---------------- U = xTb x UW^T ; V2[bs] = VW x xTb[fps[bs]] (K=64 GEMM) ----------------
__global__ __launch_bounds__(256) void uv_gemm(const ushort_t* __restrict__ xTb, const int* __restrict__ fps,
                                               const ushort_t* __restrict__ UW, const ushort_t* __restrict__ VW,
                                               ushort_t* __restrict__ U, ushort_t* __restrict__ V2){
    int tid = threadIdx.x;
    int w = tid >> 6, l = tid & 63;
    int l15 = l & 15, l4 = l >> 4;
    bool isV = blockIdx.x >= 256;
    int base = (isV ? (int)(blockIdx.x - 256) : (int)blockIdx.x)*128 + w*32;
    const ushort_t* Wh = isV ? VW : UW;
    ushort_t* out = isV ? V2 : U;

    long xrow[2];
    #pragma unroll
    for (int n=0;n<2;n++){
        int r = base + n*16 + l15;
        if (isV){ int b = r >> 10; xrow[n] = ((long)(b<<12) + fps[r]); }
        else    { xrow[n] = r; }
    }
    f32x4 acc[8][2] = {};
    #pragma unroll
    for (int ks=0; ks<2; ks++){
        int kl = ks*32 + l4*8;
        s16x8 af[8];
        #pragma unroll
        for (int m=0;m<8;m++)
            af[m] = *(const s16x8*)(Wh + (m*16 + l15)*64 + kl);
        s16x8 bv[2];
        #pragma unroll
        for (int n=0;n<2;n++)
            bv[n] = *(const s16x8*)(xTb + xrow[n]*64 + kl);
        #pragma unroll
        for (int m=0;m<8;m++)
            #pragma unroll
            for (int n=0;n<2;n++)
                acc[m][n] = __builtin_amdgcn_mfma_f32_16x16x32_bf16(af[m], bv[n], acc[m][n], 0, 0, 0);
    }
    #pragma unroll
    for (int n=0;n<2;n++){
        long radr = (long)(base + n*16 + l15)*C_;
        #pragma unroll
        for (int m=0;m<8;m++){
            f32x4 a = acc[m][n];
            uint2 st;
            st.x = (((uint32)f2bf(a[1]))<<16) | f2bf(a[0]);
            st.y = (((uint32)f2bf(a[3]))<<16) | f2bf(a[2]);
            *(uint2*)(out + radr + m*16 + l4*4) = st;
        }
    }
}

// ---------------- MFMA conv (R7-form: LDS-staged input, direct stores) ----------------
// MODE: 0 RAW | 1 PRE gelu(bn(in1)) | 2 RESID gelu(bn(in1)+in2), aux-store
//       3 GADD (U[idx]+V2[bs]) | 4 RESID_VIRT (feature gather), aux-store
// PROLOG: 0 scsh from gmem | 1 reduce pbprev[256][64] in-block (ext2, nb=64)
template<int MODE, int PROLOG>
__global__ __launch_bounds__(256) void conv_mfma(const ushort_t* in1, const ushort_t* in2, ushort_t* aux,
        ushort_t* out, const ushort_t* __restrict__ Wb, const float* __restrict__ scsh_g,
        const ushort_t* __restrict__ U, const ushort_t* __restrict__ V2,
        const ushort_t* __restrict__ xTb, const int* __restrict__ idxg, const int* __restrict__ fps,
        const float* __restrict__ pbprev, const float* __restrict__ g, const float* __restrict__ bb,
        float* __restrict__ pb, int nb, float inv_cnt){
    __shared__ ushort_t inT[16384];
    __shared__ float ss[256];
    __shared__ float sL[4][128], qL[4][128];
    int tid = threadIdx.x;
    int w = tid >> 6, l = tid & 63;
    int l15 = l & 15, l4 = l >> 4;
    long col0 = ((long)blockIdx.x << 7) + ((long)w << 5);

    if (MODE != 3){
        const char* gt = (const char*)(in1 + (((long)blockIdx.x) << 7)*C_);
        char* lb = (char*)inT;
        #pragma unroll
        for (int i=0;i<8;i++){
            int p = i*4096 + w*1024 + l*16;
            int src = p ^ (((p>>8)&7)<<4);
            gl_lds16(gt + src, lb + i*4096 + w*1024);
        }
    }

    s16x8 a2[8];
    if (MODE == 2){
        #pragma unroll
        for (int t=0;t<8;t++){
            int n = t>>2, ks = t&3;
            a2[t] = *(const s16x8*)(in2 + (col0 + n*16 + l15)*C_ + ks*32 + l4*8);
        }
    }
    if (MODE == 4){
        int bs = (int)(col0 >> 5);
        int b  = bs >> 10;
        int cc = fps[bs];
        const ushort_t* crow = xTb + ((long)(b<<12) + cc)*64;
        s16x8 cv0 = *(const s16x8*)(crow + l4*8);
        s16x8 cv1 = *(const s16x8*)(crow + 32 + l4*8);
        #pragma unroll
        for (int n=0;n<2;n++){
            int nn = idxg[col0 + n*16 + l15];
            const ushort_t* prow = xTb + ((long)(b<<12) + nn)*64;
            s16x8 p0 = *(const s16x8*)(prow + l4*8);
            s16x8 p1 = *(const s16x8*)(prow + 32 + l4*8);
            s16x8 d0, d1;
            #pragma unroll
            for (int e=0;e<8;e++){
                d0[e] = (short)f2bf(bf2f((ushort_t)p0[e]) - bf2f((ushort_t)cv0[e]));
                d1[e] = (short)f2bf(bf2f((ushort_t)p1[e]) - bf2f((ushort_t)cv1[e]));
            }
            a2[n*4+0] = d0; a2[n*4+1] = d1; a2[n*4+2] = cv0; a2[n*4+3] = cv1;
        }
    }
    if (MODE == 1 || MODE == 2 || MODE == 4){
        if (PROLOG){
            if (tid < 128){
                const float4* ps = (const float4*)(pbprev + tid*64);
                const float4* pq = (const float4*)(pbprev + (128+tid)*64);
                float s=0.f, q=0.f;
                #pragma unroll
                for (int i=0;i<16;i++){ float4 a=ps[i]; s += (a.x+a.y)+(a.z+a.w); }
                #pragma unroll
                for (int i=0;i<16;i++){ float4 a=pq[i]; q += (a.x+a.y)+(a.z+a.w); }
                float mean = s*inv_cnt, var = q*inv_cnt - mean*mean;
                float sc = g[tid]*rsqrtf(var+EPS_);
                ss[tid*2]   = sc;
                ss[tid*2+1] = bb[tid] - mean*sc;
            }
        } else {
            ss[tid] = scsh_g[tid];
        }
    }
    __syncthreads();   // staging + ss complete; in-place safe after this point

    f32x4 acc[8][2] = {};
    if (MODE == 3){
        int bs = (int)(col0 >> 5);
        int b  = bs >> 10;
        const ushort_t* vrow = V2 + (long)bs*C_;
        #pragma unroll
        for (int n=0;n<2;n++){
            int nn = idxg[col0 + n*16 + l15];
            const ushort_t* urow = U + ((long)(b*4096) + nn)*C_;
            #pragma unroll
            for (int m=0;m<8;m++){
                int oc0 = m*16 + l4*4;
                uint2 uu = *(const uint2*)(urow + oc0);
                uint2 vv = *(const uint2*)(vrow + oc0);
                acc[m][n][0] = bf2f((ushort_t)(uu.x & 0xFFFFu)) + bf2f((ushort_t)(vv.x & 0xFFFFu));
                acc[m][n][1] = bf2f((ushort_t)(uu.x >> 16))     + bf2f((ushort_t)(vv.x >> 16));
                acc[m][n][2] = bf2f((ushort_t)(uu.y & 0xFFFFu)) + bf2f((ushort_t)(vv.y & 0xFFFFu));
                acc[m][n][3] = bf2f((ushort_t)(uu.y >> 16))     + bf2f((ushort_t)(vv.y >> 16));
            }
        }
    } else {
        const char* lb = (const char*)inT;
        #pragma unroll
        for (int ks=0; ks<4; ks++){
            int kl = ks*32 + l4*8;
            s16x8 af[8];
            #pragma unroll
            for (int m=0;m<8;m++)
                af[m] = *(const s16x8*)(Wb + (m*16 + l15)*C_ + kl);
            s16x8 bv[2];
            #pragma unroll
            for (int n=0;n<2;n++){
                int q = (w*32 + n*16 + l15)*256 + ks*64 + l4*16;
                int qs = q ^ (((q>>8)&7)<<4);
                bv[n] = *(const s16x8*)(lb + qs);
            }
            if (MODE != 0){
                float sc[8], sh[8];
                const float4* sp = (const float4*)(&ss[kl*2]);
                float4 s0 = sp[0], s1 = sp[1], s2 = sp[2], s3 = sp[3];
                sc[0]=s0.x; sh[0]=s0.y; sc[1]=s0.z; sh[1]=s0.w;
                sc[2]=s1.x; sh[2]=s1.y; sc[3]=s1.z; sh[3]=s1.w;
                sc[4]=s2.x; sh[4]=s2.y; sc[5]=s2.z; sh[5]=s2.w;
                sc[6]=s3.x; sh[6]=s3.y; sc[7]=s3.z; sh[7]=s3.w;
                #pragma unroll
                for (int n=0;n<2;n++){
                    s16x8 v = bv[n];
                    if (MODE == 1){
                        #pragma unroll
                        for (int e=0;e<8;e++){
                            float f = gelu_f(fmaf(bf2f((ushort_t)v[e]), sc[e], sh[e]));
                            v[e] = (short)f2bf(f);
                        }
                    } else {
                        s16x8 a = a2[n*4+ks];
                        #pragma unroll
                        for (int e=0;e<8;e++){
                            float f = gelu_f(fmaf(bf2f((ushort_t)v[e]), sc[e], sh[e]) + bf2f((ushort_t)a[e]));
                            v[e] = (short)f2bf(f);
                        }
                    }
                    bv[n] = v;
                    if (MODE == 2 || MODE == 4)
                        *(s16x8*)(aux + (col0 + n*16 + l15)*C_ + kl) = v;   // wave-private col
                }
            }
            #pragma unroll
            for (int m=0;m<8;m++)
                #pragma unroll
                for (int n=0;n<2;n++)
                    acc[m][n] = __builtin_amdgcn_mfma_f32_16x16x32_bf16(af[m], bv[n], acc[m][n], 0, 0, 0);
        }
    }

    // ---- out stores direct (wave-private cols) ----
    #pragma unroll
    for (int n=0;n<2;n++){
        long cadr = (col0 + n*16 + l15)*C_;
        #pragma unroll
        for (int m=0;m<8;m++){
            f32x4 a = acc[m][n];
            uint2 st;
            st.x = (((uint32)f2bf(a[1]))<<16) | f2bf(a[0]);
            st.y = (((uint32)f2bf(a[3]))<<16) | f2bf(a[2]);
            *(uint2*)(out + cadr + m*16 + l4*4) = st;
        }
    }

    // ---- BN-stat partials over this block's 128 cols ----
    #pragma unroll
    for (int m=0;m<8;m++){
        #pragma unroll
        for (int r=0;r<4;r++){
            float a0=acc[m][0][r], a1=acc[m][1][r];
            float s = a0+a1;
            float q = a0*a0+a1*a1;
            #pragma unroll
            for (int off=1; off<16; off<<=1){
                s += __shfl_xor(s, off, 64);
                q += __shfl_xor(q, off, 64);
            }
            if (l15 == 0){
                sL[w][m*16 + l4*4 + r] = s;
                qL[w][m*16 + l4*4 + r] = q;
            }
        }
    }
    __syncthreads();
    if (tid < 128){
        float s = sL[0][tid] + sL[1][tid] + sL[2][tid] + sL[3][tid];
        float q = qL[0][tid] + qL[1][tid] + qL[2][tid] + qL[3][tid];
        pb[(long)tid*nb + blockIdx.x]       = s;
        pb[(long)(128+tid)*nb + blockIdx.x] = q;
    }
}

// ---------------- reduce partials[256][nb] -> (scale, shift) ----------------
__global__ __launch_bounds__(256) void reduce_fin_kernel(const float* __restrict__ pb, float* __restrict__ scsh,
                                                         const float* __restrict__ g, const float* __restrict__ bb,
                                                         float inv_cnt, int nb){
    int oc = blockIdx.x;
    float s=0.f, q=0.f;
    for (int b=threadIdx.x; b<nb; b+=256){
        s += pb[(long)oc*nb + b];
        q += pb[(long)(128+oc)*nb + b];
    }
    __shared__ float ls[256], lq[256];
    ls[threadIdx.x]=s; lq[threadIdx.x]=q;
    __syncthreads();
    #pragma unroll
    for (int st_=128; st_>0; st_>>=1){
        if (threadIdx.x < st_){ ls[threadIdx.x]+=ls[threadIdx.x+st_]; lq[threadIdx.x]+=lq[threadIdx.x+st_]; }
        __syncthreads();
    }
    if (threadIdx.x==0){
        float mean = ls[0]*inv_cnt;
        float var  = lq[0]*inv_cnt - mean*mean;
        float sc   = g[oc]*rsqrtf(var + EPS_);
        scsh[oc*2+0] = sc;
        scsh[oc*2+1] = bb[oc] - mean*sc;
    }
}

// ---------------- pool with fused resid: A2[bs][c] = max_k gelu(bn(T)+X) ----------------
__global__ __launch_bounds__(256) void pool_kernel(const ushort_t* __restrict__ T, const ushort_t* __restrict__ X,
                                                   const float* __restrict__ scsh, ushort_t* __restrict__ A2){
    long p  = (long)blockIdx.x*256 + threadIdx.x;
    long bs = p >> 6;
    int  c0 = ((int)p & 63)*2;
    float sc0=scsh[c0*2], sh0=scsh[c0*2+1], sc1=scsh[c0*2+2], sh1=scsh[c0*2+3];
    const ushort_t* tb = T + (bs*K_)*(long)C_ + c0;
    const ushort_t* xv = X + (bs*K_)*(long)C_ + c0;
    float m0 = -1e30f, m1 = -1e30f;
    #pragma unroll 4
    for (int k=0;k<K_;k++){
        uint32 tv = *(const uint32*)(tb + (long)k*C_);
        uint32 av = *(const uint32*)(xv + (long)k*C_);
        float v0 = gelu_f(fmaf(bf2f((ushort_t)(tv & 0xFFFFu)), sc0, sh0) + bf2f((ushort_t)(av & 0xFFFFu)));
        float v1 = gelu_f(fmaf(bf2f((ushort_t)(tv >> 16)),     sc1, sh1) + bf2f((ushort_t)(av >> 16)));
        m0 = fmaxf(m0, v0);
        m1 = fmaxf(m1, v1);
    }
    uint32 o = (((uint32)f2bf(m1))<<16) | f2bf(m0);
    *(uint32*)(A2 + bs*C_ + c0) = o;
}

// ---------------- out2: y[b][c][s] = gelu(bn(T)+X), LDS-tiled, coalesced ----------------
__global__ __launch_bounds__(256) void out2_kernel(const ushort_t* __restrict__ T, const ushort_t* __restrict__ X,
                                                   const float* __restrict__ scsh_g, float* __restrict__ y){
    __shared__ ushort_t Ts[16384];
    __shared__ ushort_t Xs[16384];
    __shared__ float ss[256];
    int tid = threadIdx.x, w = tid>>6, l = tid&63;
    int blk = blockIdx.x;

    {
        const char* gt = (const char*)(T + ((long)blk << 7)*C_);
        const char* gx = (const char*)(X + ((long)blk << 7)*C_);
        #pragma unroll
        for (int i=0;i<8;i++){
            int p = i*4096 + w*1024 + l*16;
            int src = p ^ (((p>>8)&7)<<4);
            gl_lds16(gt + src, (char*)Ts + i*4096 + w*1024);
            gl_lds16(gx + src, (char*)Xs + i*4096 + w*1024);
        }
    }
    ss[tid] = scsh_g[tid];
    __syncthreads();

    int b  = blk >> 3;
    int s0 = (blk & 7) * 128;
    int colL = tid & 127;
    int rep  = tid >> 7;
    #pragma unroll
    for (int cb=0; cb<8; cb++){
        int q  = colL*256 + rep*128 + cb*16;
        int qs = q ^ (((q>>8)&7)<<4);
        s16x8 tvv = *(const s16x8*)((char*)Ts + qs);
        s16x8 xvv = *(const s16x8*)((char*)Xs + qs);
        #pragma unroll
        for (int e=0;e<8;e++){
            int c = rep*64 + cb*8 + e;
            float f = gelu_f(fmaf(bf2f((ushort_t)tvv[e]), ss[c*2], ss[c*2+1]) + bf2f((ushort_t)xvv[e]));
            y[((long)(b*C_ + c))*S_ + s0 + colL] = f;
        }
    }
}

// ---------------- host ----------------
extern "C" void kernel_launch(void* const* d_in, const int* in_sizes, int n_in,
                              void* d_out, int out_size, void* d_ws, size_t ws_size,
                              hipStream_t stream){
    const float* xyz        = (const float*)d_in[0];
    const float* x          = (const float*)d_in[1];
    const int*   fps        = (const int*)d_in[2];
    const float* pre_bn_g   = (const float*)d_in[4];
    const float* pre_bn_b   = (const float*)d_in[5];
    const float* pre_ffn_g  = (const float*)d_in[7];
    const float* pre_ffn_b  = (const float*)d_in[8];
    const float* pos_bn_g   = (const float*)d_in[10];
    const float* pos_bn_b   = (const float*)d_in[11];
    const float* pos_ffn_g  = (const float*)d_in[13];
    const float* pos_ffn_b  = (const float*)d_in[14];

    float* out_xyz = (float*)d_out;
    float* out_y   = (float*)d_out + (long)B_*S_*3;

    // ws layout (bytes) — audited (same as R12):
    //   0        scsh (10240)
    //   10240    pbEa (65536) -> 75776 ; pbEb (65536) -> 141312 (within pbE reserve to 337920)
    //   337920   Wb(327680) -> 665600 | UW -> 681984 | VW -> 698368
    //   698368   idx(1MB) -> 1746944
    //   1746944  xTb(4MB) -> 5941248
    //   5941248  A2(2MB) -> 8038400
    //   8038400  pb1(2MB, ext1) THEN C2(2MB, ext2; disjoint lifetime) -> 10135552
    //   10135552 Cb(64MiB) -> 77244416
    //   77244416 X(64MiB) -> 144353280  (U = X+0 8MB, V2 = X+8MB; dead before X written)
    char* ws = (char*)d_ws;
    float*    scsh = (float*)(ws + 0);
    float*    pbEa = (float*)(ws + 10240);
    float*    pbEb = (float*)(ws + 75776);
    ushort_t* Wb   = (ushort_t*)(ws + 337920);
    ushort_t* UW   = (ushort_t*)(ws + 665600);
    ushort_t* VW   = (ushort_t*)(ws + 681984);
    int*      idx  = (int*)(ws + 698368);
    ushort_t* xTb  = (ushort_t*)(ws + 1746944);
    ushort_t* A2   = (ushort_t*)(ws + 5941248);
    float*    pb1  = (float*)(ws + 8038400);
    ushort_t* C2   = (ushort_t*)(ws + 8038400);
    ushort_t* Cb   = (ushort_t*)(ws + 10135552);
    ushort_t* X    = (ushort_t*)(ws + 77244416);
    ushort_t* U    = (ushort_t*)(ws + 77244416);
    ushort_t* V2   = (ushort_t*)(ws + 85633024);
    (void)in_sizes; (void)n_in; (void)out_size; (void)ws_size;

    const float inv1 = 1.0f/(float)NCOL1, inv2 = 1.0f/(float)NCOL2;
    const ushort_t* Wp = Wb;
    const ushort_t* Wq = Wb + 5*C_*C_;
    const int nb = 2048;

    wcvt_kernel<<<704,256,0,stream>>>((const float*)d_in[3], (const float*)d_in[6],
                                      (const float*)d_in[9], (const float*)d_in[12], Wb, UW, VW);
    transpose_kernel<<<B_*(N_/64),256,0,stream>>>(x, xTb);
    knn_kernel<<<B_*S_,256,0,stream>>>(xyz, fps, idx, out_xyz);
    uv_gemm<<<320,256,0,stream>>>(xTb, fps, UW, VW, U, V2);

    // -------- extraction 1 --------
    {
        const float* G[5]  = {pre_bn_g, pre_bn_g+C_, pre_bn_g+2*C_, pre_bn_g+3*C_, pre_ffn_g};
        const float* Bv[5] = {pre_bn_b, pre_bn_b+C_, pre_bn_b+2*C_, pre_bn_b+3*C_, pre_ffn_b};
        conv_mfma<3,0><<<nb,256,0,stream>>>(nullptr, nullptr, nullptr, Cb, nullptr, nullptr,
                                            U, V2, nullptr, idx, fps, nullptr, nullptr, nullptr, pb1, nb, inv1);
        reduce_fin_kernel<<<128,256,0,stream>>>(pb1, scsh+0*256, G[0], Bv[0], inv1, nb);
        conv_mfma<1,0><<<nb,256,0,stream>>>(Cb, nullptr, nullptr, Cb, Wp+1*C_*C_, scsh+0*256,
                                            nullptr, nullptr, nullptr, nullptr, nullptr, nullptr, nullptr, nullptr, pb1, nb, inv1);
        reduce_fin_kernel<<<128,256,0,stream>>>(pb1, scsh+1*256, G[1], Bv[1], inv1, nb);
        conv_mfma<4,0><<<nb,256,0,stream>>>(Cb, nullptr, X, Cb, Wp+2*C_*C_, scsh+1*256,
                                            nullptr, nullptr, xTb, idx, fps, nullptr, nullptr, nullptr, pb1, nb, inv1);
        reduce_fin_kernel<<<128,256,0,stream>>>(pb1, scsh+2*256, G[2], Bv[2], inv1, nb);
        conv_mfma<1,0><<<nb,256,0,stream>>>(Cb, nullptr, nullptr, Cb, Wp+3*C_*C_, scsh+2*256,
                                            nullptr, nullptr, nullptr, nullptr, nullptr, nullptr, nullptr, nullptr, pb1, nb, inv1);
        reduce_fin_kernel<<<128,256,0,stream>>>(pb1, scsh+3*256, G[3], Bv[3], inv1, nb);
        conv_mfma<2,0><<<nb,256,0,stream>>>(Cb, X, X, Cb, Wp+4*C_*C_, scsh+3*256,
                                            nullptr, nullptr, nullptr, nullptr, nullptr, nullptr, nullptr, nullptr, pb1, nb, inv1);
        reduce_fin_kernel<<<128,256,0,stream>>>(pb1, scsh+4*256, G[4], Bv[4], inv1, nb);
        pool_kernel<<<(NCOL2*64)/256,256,0,stream>>>(Cb, X, scsh+4*256, A2);
    }

    // -------- extraction 2: split launches, BN reduce fused into consumer prologue --------
    {
        const float* G[5]  = {pos_bn_g, pos_bn_g+C_, pos_bn_g+2*C_, pos_bn_g+3*C_, pos_ffn_g};
        const float* Bv[5] = {pos_bn_b, pos_bn_b+C_, pos_bn_b+2*C_, pos_bn_b+3*C_, pos_ffn_b};
        const int nb2 = 64;
        conv_mfma<0,0><<<nb2,256,0,stream>>>(A2, nullptr, nullptr, C2, Wq+0*C_*C_, nullptr,
                                             nullptr, nullptr, nullptr, nullptr, nullptr, nullptr, nullptr, nullptr, pbEa, nb2, inv2);
        conv_mfma<1,1><<<nb2,256,0,stream>>>(C2, nullptr, nullptr, C2, Wq+1*C_*C_, nullptr,
                                             nullptr, nullptr, nullptr, nullptr, nullptr, pbEa, G[0], Bv[0], pbEb, nb2, inv2);
        conv_mfma<2,1><<<nb2,256,0,stream>>>(C2, A2, A2, C2, Wq+2*C_*C_, nullptr,
                                             nullptr, nullptr, nullptr, nullptr, nullptr, pbEb, G[1], Bv[1], pbEa, nb2, inv2);
        conv_mfma<1,1><<<nb2,256,0,stream>>>(C2, nullptr, nullptr, C2, Wq+3*C_*C_, nullptr,
                                             nullptr, nullptr, nullptr, nullptr, nullptr, pbEa, G[2], Bv[2], pbEb, nb2, inv2);
        conv_mfma<2,1><<<nb2,256,0,stream>>>(C2, A2, A2, C2, Wq+4*C_*C_, nullptr,
                                             nullptr, nullptr, nullptr, nullptr, nullptr, pbEb, G[3], Bv[3], pbEa, nb2, inv2);
        reduce_fin_kernel<<<128,256,0,stream>>>(pbEa, scsh+5*256, G[4], Bv[4], inv2, nb2);
        out2_kernel<<<64,256,0,stream>>>(C2, A2, scsh+5*256, out_y);
    }
}

// Round 16
// 571.137 us; speedup vs baseline: 1.2737x; 1.0330x over previous
//
#include <hip/hip_runtime.h>
#include <math.h>

typedef unsigned short ushort_t;
typedef unsigned long long u64;
typedef unsigned int uint32;

#define B_ 8
#define N_ 4096
#define S_ 1024
#define K_ 32
#define C_ 128
#define NCOL1 (B_*S_*K_)   // 262144
#define NCOL2 (B_*S_)      // 8192
#define EPS_ 1e-5f

typedef short s16x8 __attribute__((ext_vector_type(8)));
typedef float f32x4 __attribute__((ext_vector_type(4)));

__device__ __forceinline__ float bf2f(ushort_t u){ return __uint_as_float(((uint32)u)<<16); }
__device__ __forceinline__ ushort_t f2bf(float f){
    uint32 x = __float_as_uint(f);
    return (ushort_t)((x + 0x7FFFu + ((x>>16)&1u)) >> 16);
}
__device__ __forceinline__ float gelu_f(float v){
    float az = fabsf(v)*0.70710678118654752f;
    float t  = __builtin_amdgcn_rcpf(fmaf(0.3275911f, az, 1.0f));
    float p  = fmaf(fmaf(fmaf(fmaf(1.061405429f, t, -1.453152027f), t, 1.421413741f), t,
                   -0.284496736f), t, 0.254829592f)*t;
    float e  = __expf(-az*az);
    float er = fmaf(-p, e, 1.0f);
    float s  = (v < 0.0f) ? -er : er;
    return 0.5f*v*(1.0f+s);
}
__device__ __forceinline__ u64 shfl_xor_u64(u64 v, int m){
    int lo = __shfl_xor((int)(v & 0xFFFFFFFFull), m, 64);
    int hi = __shfl_xor((int)(v >> 32), m, 64);
    return (((u64)(uint32)hi) << 32) | (uint32)lo;
}
__device__ __forceinline__ void gl_lds16(const char* gp, char* lp){
    __builtin_amdgcn_global_load_lds((const __attribute__((address_space(1))) void*)gp,
                                     (__attribute__((address_space(3))) void*)lp, 16, 0, 0);
}

// ---------------- transpose x (B,64,N) -> xTb (B,N,64) bf16 ----------------
__global__ __launch_bounds__(256) void transpose_kernel(const float* __restrict__ x, ushort_t* __restrict__ xTb){
    __shared__ float t[64][65];
    int b  = blockIdx.x >> 6;
    int n0 = (blockIdx.x & 63) * 64;
    int tx = threadIdx.x & 63, ty = threadIdx.x >> 6;
    #pragma unroll
    for (int i=0;i<16;i++){
        int c = i*4 + ty;
        t[c][tx] = x[((long)(b*64 + c))*N_ + n0 + tx];
    }
    __syncthreads();
    #pragma unroll
    for (int i=0;i<16;i++){
        int n = i*4 + ty;
        xTb[((long)(b*N_ + n0 + n))*64 + tx] = f2bf(t[tx][n]);
    }
}

// ---------------- KNN: 1-pass radix bucket (1024 bins) + exact serial boundary select ------
// Rank-31's boundary bin typically holds O(1..10) elements for point-cloud distances; the
// serial candidate path is exact for cb<=1024 (cb >= need guaranteed since b1 holds rank 31),
// with the 32-round exact fallback above. Drops pass-2 histogram entirely: LDS 26->14 KB.
__global__ __launch_bounds__(256) void knn_kernel(const float* __restrict__ xyz, const int* __restrict__ fps,
                                                  int* __restrict__ idxg, float* __restrict__ newxyz){
    __shared__ uint32 hist[1024];
    __shared__ u64    cand[1024];
    __shared__ u64    out_keys[64];
    __shared__ uint32 csum[256];
    __shared__ uint32 wtot[4];
    __shared__ uint32 shv[8];          // 0:b1 1:cl1 4:sel 5:cand
    __shared__ u64    wred[4];
    __shared__ u64    winner;

    int tid = threadIdx.x;
    int wv = tid >> 6, l = tid & 63;
    int bs = blockIdx.x;
    int b  = bs >> 10;
    int qi = fps[bs];
    const float* qb = xyz + ((long)b*N_ + qi)*3;
    float qx = qb[0], qy = qb[1], qz = qb[2];
    if (tid < 3) newxyz[(long)bs*3 + tid] = qb[tid];
    const float* xb = xyz + (long)b*N_*3;

    for (int i=tid;i<1024;i+=256) hist[i]=0;
    if (tid < 8) shv[tid]=0;
    __syncthreads();

    // distances (regs) + histogram over float bits 30..21 (1024 bins)
    uint32 dbits[16];
    #pragma unroll
    for (int i=0;i<16;i++){
        int n = i*256 + tid;
        float dx = xb[n*3+0]-qx, dy = xb[n*3+1]-qy, dz = xb[n*3+2]-qz;
        float d = dx*dx + dy*dy + dz*dz;
        dbits[i] = __float_as_uint(d);
        atomicAdd(&hist[dbits[i]>>21], 1u);
    }
    __syncthreads();

    // scan (4 bins/thread), find bin of rank 31
    {
        uint32 h4[4]; uint32 csumv=0;
        #pragma unroll
        for (int i=0;i<4;i++){ h4[i]=hist[tid*4+i]; csumv+=h4[i]; }
        uint32 sc = csumv;
        #pragma unroll
        for (int off=1; off<64; off<<=1){ uint32 o=__shfl_up(sc,off,64); if (l>=off) sc+=o; }
        if (l==63) wtot[wv]=sc;
        csum[tid]=sc;
        __syncthreads();
        uint32 base=0;
        for (int w2=0; w2<wv; w2++) base += wtot[w2];
        uint32 cum = base + csum[tid] - csumv;
        #pragma unroll
        for (int i=0;i<4;i++){
            if (cum <= 31u && 31u < cum + h4[i]){ shv[0]=(uint32)(tid*4+i); shv[1]=cum; }
            cum += h4[i];
        }
    }
    __syncthreads();
    uint32 b1 = shv[0], cl1 = shv[1];

    // collect sure winners (< b1) and boundary candidates (== b1)
    #pragma unroll
    for (int i=0;i<16;i++){
        uint32 u = dbits[i];
        int n = i*256 + tid;
        uint32 bb1 = u >> 21;
        if (bb1 > b1) continue;
        u64 key = (((u64)u)<<32) | (uint32)n;
        if (bb1 < b1){
            uint32 p = atomicAdd(&shv[4],1u); out_keys[p] = key;
        } else {
            uint32 p = atomicAdd(&shv[5],1u); if (p < 1024u) cand[p] = key;
        }
    }
    __syncthreads();

    if (shv[5] > 1024u){
        // exact fallback (massive boundary bin): serial 32-round block argmin
        uint32 alive = 0xFFFFu;
        for (int r=0;r<K_;r++){
            u64 lmin = ~0ull;
            #pragma unroll
            for (int i=0;i<16;i++){
                u64 k = (((u64)dbits[i])<<32) | (uint32)(i*256+tid);
                if (((alive>>i)&1u) && k < lmin) lmin = k;
            }
            #pragma unroll
            for (int off=32; off>=1; off>>=1){
                u64 o = shfl_xor_u64(lmin, off);
                if (o < lmin) lmin = o;
            }
            if (l == 0) wred[wv] = lmin;
            __syncthreads();
            if (tid == 0){
                u64 m = wred[0];
                if (wred[1]<m) m=wred[1];
                if (wred[2]<m) m=wred[2];
                if (wred[3]<m) m=wred[3];
                winner = m;
                idxg[(long)bs*K_ + r] = (int)(m & 0xFFFFFFFFull);
            }
            __syncthreads();
            u64 w = winner;
            #pragma unroll
            for (int i=0;i<16;i++){
                u64 k = (((u64)dbits[i])<<32) | (uint32)(i*256+tid);
                if (k == w) alive &= ~(1u<<i);
            }
        }
    } else if (wv == 0){
        uint32 cb   = shv[5];
        uint32 need = 32u - cl1;       // >=1 and <=cb by construction
        for (uint32 r=0; r<need; r++){
            u64 lmin = ~0ull;
            for (uint32 s=l; s<cb; s+=64){ u64 kk = cand[s]; if (kk < lmin) lmin = kk; }
            #pragma unroll
            for (int off=32; off>=1; off>>=1){
                u64 o = shfl_xor_u64(lmin, off);
                if (o < lmin) lmin = o;
            }
            for (uint32 s=l; s<cb; s+=64){ if (cand[s]==lmin) cand[s] = ~0ull; }
            if (l==0) out_keys[cl1 + r] = lmin;
        }
        u64 key = (l < 32) ? out_keys[l] : ~0ull;
        #pragma unroll
        for (uint32 k=2; k<=64; k<<=1){
            bool dir = ((l & k)==0);
            #pragma unroll
            for (uint32 j=k>>1; j>=1; j>>=1){
                u64 o = shfl_xor_u64(key, j);
                bool lower = ((l & j)==0);
                u64 mn = (key < o) ? key : o;
                u64 mx = (key < o) ? o : key;
                key = (lower == dir) ? mn : mx;
            }
        }
        if (l < 32) idxg[(long)bs*K_ + l] = (int)(key & 0xFFFFFFFFull);
    }
}

// ---------------- weights f32 -> bf16 (10 mats) + UW/VW halves of W1 ----------------
__global__ __launch_bounds__(256) void wcvt_kernel(const float* __restrict__ pcw, const float* __restrict__ pfw,
                                                   const float* __restrict__ qcw, const float* __restrict__ qfw,
                                                   ushort_t* __restrict__ Wb, ushort_t* __restrict__ UW,
                                                   ushort_t* __restrict__ VW){
    int i = blockIdx.x*256 + threadIdx.x;   // 0 .. 180223
    if (i < 163840){
        int mat = i >> 14;
        int r = i & 16383;
        float v;
        if (mat < 4)       v = pcw[i];
        else if (mat == 4) v = pfw[r];
        else if (mat < 9)  v = qcw[i - 5*16384];
        else               v = qfw[r];
        Wb[i] = f2bf(v);
    } else {
        int j = i - 163840;                 // 0..16383
        int jj = j & 8191;
        int oc = jj >> 6, c = jj & 63;
        if (j < 8192) UW[jj] = f2bf(pcw[oc*128 + c]);
        else          VW[jj] = f2bf(pcw[oc*128 + 64 + c] - pcw[oc*128 + c]);
    }
}

// ---------------- U = xTb x UW^T ; V2[bs] = VW x xTb[fps[bs]] (K=64 GEMM) ----------------
__global__ __launch_bounds__(256) void uv_gemm(const ushort_t* __restrict__ xTb, const int* __restrict__ fps,
                                               const ushort_t* __restrict__ UW, const ushort_t* __restrict__ VW,
                                               ushort_t* __restrict__ U, ushort_t* __restrict__ V2){
    int tid = threadIdx.x;
    int w = tid >> 6, l = tid & 63;
    int l15 = l & 15, l4 = l >> 4;
    bool isV = blockIdx.x >= 256;
    int base = (isV ? (int)(blockIdx.x - 256) : (int)blockIdx.x)*128 + w*32;
    const ushort_t* Wh = isV ? VW : UW;
    ushort_t* out = isV ? V2 : U;

    long xrow[2];
    #pragma unroll
    for (int n=0;n<2;n++){
        int r = base + n*16 + l15;
        if (isV){ int b = r >> 10; xrow[n] = ((long)(b<<12) + fps[r]); }
        else    { xrow[n] = r; }
    }
    f32x4 acc[8][2] = {};
    #pragma unroll
    for (int ks=0; ks<2; ks++){
        int kl = ks*32 + l4*8;
        s16x8 af[8];
        #pragma unroll
        for (int m=0;m<8;m++)
            af[m] = *(const s16x8*)(Wh + (m*16 + l15)*64 + kl);
        s16x8 bv[2];
        #pragma unroll
        for (int n=0;n<2;n++)
            bv[n] = *(const s16x8*)(xTb + xrow[n]*64 + kl);
        #pragma unroll
        for (int m=0;m<8;m++)
            #pragma unroll
            for (int n=0;n<2;n++)
                acc[m][n] = __builtin_amdgcn_mfma_f32_16x16x32_bf16(af[m], bv[n], acc[m][n], 0, 0, 0);
    }
    #pragma unroll
    for (int n=0;n<2;n++){
        long radr = (long)(base + n*16 + l15)*C_;
        #pragma unroll
        for (int m=0;m<8;m++){
            f32x4 a = acc[m][n];
            uint2 st;
            st.x = (((uint32)f2bf(a[1]))<<16) | f2bf(a[0]);
            st.y = (((uint32)f2bf(a[3]))<<16) | f2bf(a[2]);
            *(uint2*)(out + radr + m*16 + l4*4) = st;
        }
    }
}

// ---------------- MFMA conv (R7-form: LDS-staged input, direct stores) ----------------
// MODE: 0 RAW | 1 PRE gelu(bn(in1)) | 2 RESID gelu(bn(in1)+in2), aux-store
//       3 GADD (U[idx]+V2[bs]) | 4 RESID_VIRT (feature gather), aux-store
// PROLOG: 0 scsh from gmem | 1 reduce pbprev[256][64] in-block (ext2, nb=64)
template<int MODE, int PROLOG>
__global__ __launch_bounds__(256) void conv_mfma(const ushort_t* in1, const ushort_t* in2, ushort_t* aux,
        ushort_t* out, const ushort_t* __restrict__ Wb, const float* __restrict__ scsh_g,
        const ushort_t* __restrict__ U, const ushort_t* __restrict__ V2,
        const ushort_t* __restrict__ xTb, const int* __restrict__ idxg, const int* __restrict__ fps,
        const float* __restrict__ pbprev, const float* __restrict__ g, const float* __restrict__ bb,
        float* __restrict__ pb, int nb, float inv_cnt){
    __shared__ ushort_t inT[16384];
    __shared__ float ss[256];
    __shared__ float sL[4][128], qL[4][128];
    int tid = threadIdx.x;
    int w = tid >> 6, l = tid & 63;
    int l15 = l & 15, l4 = l >> 4;
    long col0 = ((long)blockIdx.x << 7) + ((long)w << 5);

    if (MODE != 3){
        const char* gt = (const char*)(in1 + (((long)blockIdx.x) << 7)*C_);
        char* lb = (char*)inT;
        #pragma unroll
        for (int i=0;i<8;i++){
            int p = i*4096 + w*1024 + l*16;
            int src = p ^ (((p>>8)&7)<<4);
            gl_lds16(gt + src, lb + i*4096 + w*1024);
        }
    }

    s16x8 a2[8];
    if (MODE == 2){
        #pragma unroll
        for (int t=0;t<8;t++){
            int n = t>>2, ks = t&3;
            a2[t] = *(const s16x8*)(in2 + (col0 + n*16 + l15)*C_ + ks*32 + l4*8);
        }
    }
    if (MODE == 4){
        int bs = (int)(col0 >> 5);
        int b  = bs >> 10;
        int cc = fps[bs];
        const ushort_t* crow = xTb + ((long)(b<<12) + cc)*64;
        s16x8 cv0 = *(const s16x8*)(crow + l4*8);
        s16x8 cv1 = *(const s16x8*)(crow + 32 + l4*8);
        #pragma unroll
        for (int n=0;n<2;n++){
            int nn = idxg[col0 + n*16 + l15];
            const ushort_t* prow = xTb + ((long)(b<<12) + nn)*64;
            s16x8 p0 = *(const s16x8*)(prow + l4*8);
            s16x8 p1 = *(const s16x8*)(prow + 32 + l4*8);
            s16x8 d0, d1;
            #pragma unroll
            for (int e=0;e<8;e++){
                d0[e] = (short)f2bf(bf2f((ushort_t)p0[e]) - bf2f((ushort_t)cv0[e]));
                d1[e] = (short)f2bf(bf2f((ushort_t)p1[e]) - bf2f((ushort_t)cv1[e]));
            }
            a2[n*4+0] = d0; a2[n*4+1] = d1; a2[n*4+2] = cv0; a2[n*4+3] = cv1;
        }
    }
    if (MODE == 1 || MODE == 2 || MODE == 4){
        if (PROLOG){
            if (tid < 128){
                const float4* ps = (const float4*)(pbprev + tid*64);
                const float4* pq = (const float4*)(pbprev + (128+tid)*64);
                float s=0.f, q=0.f;
                #pragma unroll
                for (int i=0;i<16;i++){ float4 a=ps[i]; s += (a.x+a.y)+(a.z+a.w); }
                #pragma unroll
                for (int i=0;i<16;i++){ float4 a=pq[i]; q += (a.x+a.y)+(a.z+a.w); }
                float mean = s*inv_cnt, var = q*inv_cnt - mean*mean;
                float sc = g[tid]*rsqrtf(var+EPS_);
                ss[tid*2]   = sc;
                ss[tid*2+1] = bb[tid] - mean*sc;
            }
        } else {
            ss[tid] = scsh_g[tid];
        }
    }
    __syncthreads();   // staging + ss complete; in-place safe after this point

    f32x4 acc[8][2] = {};
    if (MODE == 3){
        int bs = (int)(col0 >> 5);
        int b  = bs >> 10;
        const ushort_t* vrow = V2 + (long)bs*C_;
        #pragma unroll
        for (int n=0;n<2;n++){
            int nn = idxg[col0 + n*16 + l15];
            const ushort_t* urow = U + ((long)(b*4096) + nn)*C_;
            #pragma unroll
            for (int m=0;m<8;m++){
                int oc0 = m*16 + l4*4;
                uint2 uu = *(const uint2*)(urow + oc0);
                uint2 vv = *(const uint2*)(vrow + oc0);
                acc[m][n][0] = bf2f((ushort_t)(uu.x & 0xFFFFu)) + bf2f((ushort_t)(vv.x & 0xFFFFu));
                acc[m][n][1] = bf2f((ushort_t)(uu.x >> 16))     + bf2f((ushort_t)(vv.x >> 16));
                acc[m][n][2] = bf2f((ushort_t)(uu.y & 0xFFFFu)) + bf2f((ushort_t)(vv.y & 0xFFFFu));
                acc[m][n][3] = bf2f((ushort_t)(uu.y >> 16))     + bf2f((ushort_t)(vv.y >> 16));
            }
        }
    } else {
        const char* lb = (const char*)inT;
        #pragma unroll
        for (int ks=0; ks<4; ks++){
            int kl = ks*32 + l4*8;
            s16x8 af[8];
            #pragma unroll
            for (int m=0;m<8;m++)
                af[m] = *(const s16x8*)(Wb + (m*16 + l15)*C_ + kl);
            s16x8 bv[2];
            #pragma unroll
            for (int n=0;n<2;n++){
                int q = (w*32 + n*16 + l15)*256 + ks*64 + l4*16;
                int qs = q ^ (((q>>8)&7)<<4);
                bv[n] = *(const s16x8*)(lb + qs);
            }
            if (MODE != 0){
                float sc[8], sh[8];
                const float4* sp = (const float4*)(&ss[kl*2]);
                float4 s0 = sp[0], s1 = sp[1], s2 = sp[2], s3 = sp[3];
                sc[0]=s0.x; sh[0]=s0.y; sc[1]=s0.z; sh[1]=s0.w;
                sc[2]=s1.x; sh[2]=s1.y; sc[3]=s1.z; sh[3]=s1.w;
                sc[4]=s2.x; sh[4]=s2.y; sc[5]=s2.z; sh[5]=s2.w;
                sc[6]=s3.x; sh[6]=s3.y; sc[7]=s3.z; sh[7]=s3.w;
                #pragma unroll
                for (int n=0;n<2;n++){
                    s16x8 v = bv[n];
                    if (MODE == 1){
                        #pragma unroll
                        for (int e=0;e<8;e++){
                            float f = gelu_f(fmaf(bf2f((ushort_t)v[e]), sc[e], sh[e]));
                            v[e] = (short)f2bf(f);
                        }
                    } else {
                        s16x8 a = a2[n*4+ks];
                        #pragma unroll
                        for (int e=0;e<8;e++){
                            float f = gelu_f(fmaf(bf2f((ushort_t)v[e]), sc[e], sh[e]) + bf2f((ushort_t)a[e]));
                            v[e] = (short)f2bf(f);
                        }
                    }
                    bv[n] = v;
                    if (MODE == 2 || MODE == 4)
                        *(s16x8*)(aux + (col0 + n*16 + l15)*C_ + kl) = v;   // wave-private col
                }
            }
            #pragma unroll
            for (int m=0;m<8;m++)
                #pragma unroll
                for (int n=0;n<2;n++)
                    acc[m][n] = __builtin_amdgcn_mfma_f32_16x16x32_bf16(af[m], bv[n], acc[m][n], 0, 0, 0);
        }
    }

    // ---- out stores direct (wave-private cols) ----
    #pragma unroll
    for (int n=0;n<2;n++){
        long cadr = (col0 + n*16 + l15)*C_;
        #pragma unroll
        for (int m=0;m<8;m++){
            f32x4 a = acc[m][n];
            uint2 st;
            st.x = (((uint32)f2bf(a[1]))<<16) | f2bf(a[0]);
            st.y = (((uint32)f2bf(a[3]))<<16) | f2bf(a[2]);
            *(uint2*)(out + cadr + m*16 + l4*4) = st;
        }
    }

    // ---- BN-stat partials over this block's 128 cols ----
    #pragma unroll
    for (int m=0;m<8;m++){
        #pragma unroll
        for (int r=0;r<4;r++){
            float a0=acc[m][0][r], a1=acc[m][1][r];
            float s = a0+a1;
            float q = a0*a0+a1*a1;
            #pragma unroll
            for (int off=1; off<16; off<<=1){
                s += __shfl_xor(s, off, 64);
                q += __shfl_xor(q, off, 64);
            }
            if (l15 == 0){
                sL[w][m*16 + l4*4 + r] = s;
                qL[w][m*16 + l4*4 + r] = q;
            }
        }
    }
    __syncthreads();
    if (tid < 128){
        float s = sL[0][tid] + sL[1][tid] + sL[2][tid] + sL[3][tid];
        float q = qL[0][tid] + qL[1][tid] + qL[2][tid] + qL[3][tid];
        pb[(long)tid*nb + blockIdx.x]       = s;
        pb[(long)(128+tid)*nb + blockIdx.x] = q;
    }
}

// ---------------- reduce partials[256][nb] -> (scale, shift) ----------------
__global__ __launch_bounds__(256) void reduce_fin_kernel(const float* __restrict__ pb, float* __restrict__ scsh,
                                                         const float* __restrict__ g, const float* __restrict__ bb,
                                                         float inv_cnt, int nb){
    int oc = blockIdx.x;
    float s=0.f, q=0.f;
    for (int b=threadIdx.x; b<nb; b+=256){
        s += pb[(long)oc*nb + b];
        q += pb[(long)(128+oc)*nb + b];
    }
    __shared__ float ls[256], lq[256];
    ls[threadIdx.x]=s; lq[threadIdx.x]=q;
    __syncthreads();
    #pragma unroll
    for (int st_=128; st_>0; st_>>=1){
        if (threadIdx.x < st_){ ls[threadIdx.x]+=ls[threadIdx.x+st_]; lq[threadIdx.x]+=lq[threadIdx.x+st_]; }
        __syncthreads();
    }
    if (threadIdx.x==0){
        float mean = ls[0]*inv_cnt;
        float var  = lq[0]*inv_cnt - mean*mean;
        float sc   = g[oc]*rsqrtf(var + EPS_);
        scsh[oc*2+0] = sc;
        scsh[oc*2+1] = bb[oc] - mean*sc;
    }
}

// ---------------- pool with fused resid: A2[bs][c] = max_k gelu(bn(T)+X) ----------------
__global__ __launch_bounds__(256) void pool_kernel(const ushort_t* __restrict__ T, const ushort_t* __restrict__ X,
                                                   const float* __restrict__ scsh, ushort_t* __restrict__ A2){
    long p  = (long)blockIdx.x*256 + threadIdx.x;
    long bs = p >> 6;
    int  c0 = ((int)p & 63)*2;
    float sc0=scsh[c0*2], sh0=scsh[c0*2+1], sc1=scsh[c0*2+2], sh1=scsh[c0*2+3];
    const ushort_t* tb = T + (bs*K_)*(long)C_ + c0;
    const ushort_t* xv = X + (bs*K_)*(long)C_ + c0;
    float m0 = -1e30f, m1 = -1e30f;
    #pragma unroll 4
    for (int k=0;k<K_;k++){
        uint32 tv = *(const uint32*)(tb + (long)k*C_);
        uint32 av = *(const uint32*)(xv + (long)k*C_);
        float v0 = gelu_f(fmaf(bf2f((ushort_t)(tv & 0xFFFFu)), sc0, sh0) + bf2f((ushort_t)(av & 0xFFFFu)));
        float v1 = gelu_f(fmaf(bf2f((ushort_t)(tv >> 16)),     sc1, sh1) + bf2f((ushort_t)(av >> 16)));
        m0 = fmaxf(m0, v0);
        m1 = fmaxf(m1, v1);
    }
    uint32 o = (((uint32)f2bf(m1))<<16) | f2bf(m0);
    *(uint32*)(A2 + bs*C_ + c0) = o;
}

// ---------------- out2: y[b][c][s] = gelu(bn(T)+X), LDS-tiled, coalesced ----------------
__global__ __launch_bounds__(256) void out2_kernel(const ushort_t* __restrict__ T, const ushort_t* __restrict__ X,
                                                   const float* __restrict__ scsh_g, float* __restrict__ y){
    __shared__ ushort_t Ts[16384];
    __shared__ ushort_t Xs[16384];
    __shared__ float ss[256];
    int tid = threadIdx.x, w = tid>>6, l = tid&63;
    int blk = blockIdx.x;

    {
        const char* gt = (const char*)(T + ((long)blk << 7)*C_);
        const char* gx = (const char*)(X + ((long)blk << 7)*C_);
        #pragma unroll
        for (int i=0;i<8;i++){
            int p = i*4096 + w*1024 + l*16;
            int src = p ^ (((p>>8)&7)<<4);
            gl_lds16(gt + src, (char*)Ts + i*4096 + w*1024);
            gl_lds16(gx + src, (char*)Xs + i*4096 + w*1024);
        }
    }
    ss[tid] = scsh_g[tid];
    __syncthreads();

    int b  = blk >> 3;
    int s0 = (blk & 7) * 128;
    int colL = tid & 127;
    int rep  = tid >> 7;
    #pragma unroll
    for (int cb=0; cb<8; cb++){
        int q  = colL*256 + rep*128 + cb*16;
        int qs = q ^ (((q>>8)&7)<<4);
        s16x8 tvv = *(const s16x8*)((char*)Ts + qs);
        s16x8 xvv = *(const s16x8*)((char*)Xs + qs);
        #pragma unroll
        for (int e=0;e<8;e++){
            int c = rep*64 + cb*8 + e;
            float f = gelu_f(fmaf(bf2f((ushort_t)tvv[e]), ss[c*2], ss[c*2+1]) + bf2f((ushort_t)xvv[e]));
            y[((long)(b*C_ + c))*S_ + s0 + colL] = f;
        }
    }
}

// ---------------- host ----------------
extern "C" void kernel_launch(void* const* d_in, const int* in_sizes, int n_in,
                              void* d_out, int out_size, void* d_ws, size_t ws_size,
                              hipStream_t stream){
    const float* xyz        = (const float*)d_in[0];
    const float* x          = (const float*)d_in[1];
    const int*   fps        = (const int*)d_in[2];
    const float* pre_bn_g   = (const float*)d_in[4];
    const float* pre_bn_b   = (const float*)d_in[5];
    const float* pre_ffn_g  = (const float*)d_in[7];
    const float* pre_ffn_b  = (const float*)d_in[8];
    const float* pos_bn_g   = (const float*)d_in[10];
    const float* pos_bn_b   = (const float*)d_in[11];
    const float* pos_ffn_g  = (const float*)d_in[13];
    const float* pos_ffn_b  = (const float*)d_in[14];

    float* out_xyz = (float*)d_out;
    float* out_y   = (float*)d_out + (long)B_*S_*3;

    // ws layout (bytes) — audited (same as R15):
    //   0        scsh (10240)
    //   10240    pbEa (65536) -> 75776 ; pbEb (65536) -> 141312 (reserve to 337920)
    //   337920   Wb(327680) -> 665600 | UW -> 681984 | VW -> 698368
    //   698368   idx(1MB) -> 1746944
    //   1746944  xTb(4MB) -> 5941248
    //   5941248  A2(2MB) -> 8038400
    //   8038400  pb1(2MB, ext1) THEN C2(2MB, ext2; disjoint lifetime) -> 10135552
    //   10135552 Cb(64MiB) -> 77244416
    //   77244416 X(64MiB) -> 144353280  (U = X+0 8MB, V2 = X+8MB; dead before X written)
    char* ws = (char*)d_ws;
    float*    scsh = (float*)(ws + 0);
    float*    pbEa = (float*)(ws + 10240);
    float*    pbEb = (float*)(ws + 75776);
    ushort_t* Wb   = (ushort_t*)(ws + 337920);
    ushort_t* UW   = (ushort_t*)(ws + 665600);
    ushort_t* VW   = (ushort_t*)(ws + 681984);
    int*      idx  = (int*)(ws + 698368);
    ushort_t* xTb  = (ushort_t*)(ws + 1746944);
    ushort_t* A2   = (ushort_t*)(ws + 5941248);
    float*    pb1  = (float*)(ws + 8038400);
    ushort_t* C2   = (ushort_t*)(ws + 8038400);
    ushort_t* Cb   = (ushort_t*)(ws + 10135552);
    ushort_t* X    = (ushort_t*)(ws + 77244416);
    ushort_t* U    = (ushort_t*)(ws + 77244416);
    ushort_t* V2   = (ushort_t*)(ws + 85633024);
    (void)in_sizes; (void)n_in; (void)out_size; (void)ws_size;

    const float inv1 = 1.0f/(float)NCOL1, inv2 = 1.0f/(float)NCOL2;
    const ushort_t* Wp = Wb;
    const ushort_t* Wq = Wb + 5*C_*C_;
    const int nb = 2048;

    wcvt_kernel<<<704,256,0,stream>>>((const float*)d_in[3], (const float*)d_in[6],
                                      (const float*)d_in[9], (const float*)d_in[12], Wb, UW, VW);
    transpose_kernel<<<B_*(N_/64),256,0,stream>>>(x, xTb);
    knn_kernel<<<B_*S_,256,0,stream>>>(xyz, fps, idx, out_xyz);
    uv_gemm<<<320,256,0,stream>>>(xTb, fps, UW, VW, U, V2);

    // -------- extraction 1 --------
    {
        const float* G[5]  = {pre_bn_g, pre_bn_g+C_, pre_bn_g+2*C_, pre_bn_g+3*C_, pre_ffn_g};
        const float* Bv[5] = {pre_bn_b, pre_bn_b+C_, pre_bn_b+2*C_, pre_bn_b+3*C_, pre_ffn_b};
        conv_mfma<3,0><<<nb,256,0,stream>>>(nullptr, nullptr, nullptr, Cb, nullptr, nullptr,
                                            U, V2, nullptr, idx, fps, nullptr, nullptr, nullptr, pb1, nb, inv1);
        reduce_fin_kernel<<<128,256,0,stream>>>(pb1, scsh+0*256, G[0], Bv[0], inv1, nb);
        conv_mfma<1,0><<<nb,256,0,stream>>>(Cb, nullptr, nullptr, Cb, Wp+1*C_*C_, scsh+0*256,
                                            nullptr, nullptr, nullptr, nullptr, nullptr, nullptr, nullptr, nullptr, pb1, nb, inv1);
        reduce_fin_kernel<<<128,256,0,stream>>>(pb1, scsh+1*256, G[1], Bv[1], inv1, nb);
        conv_mfma<4,0><<<nb,256,0,stream>>>(Cb, nullptr, X, Cb, Wp+2*C_*C_, scsh+1*256,
                                            nullptr, nullptr, xTb, idx, fps, nullptr, nullptr, nullptr, pb1, nb, inv1);
        reduce_fin_kernel<<<128,256,0,stream>>>(pb1, scsh+2*256, G[2], Bv[2], inv1, nb);
        conv_mfma<1,0><<<nb,256,0,stream>>>(Cb, nullptr, nullptr, Cb, Wp+3*C_*C_, scsh+2*256,
                                            nullptr, nullptr, nullptr, nullptr, nullptr, nullptr, nullptr, nullptr, pb1, nb, inv1);
        reduce_fin_kernel<<<128,256,0,stream>>>(pb1, scsh+3*256, G[3], Bv[3], inv1, nb);
        conv_mfma<2,0><<<nb,256,0,stream>>>(Cb, X, X, Cb, Wp+4*C_*C_, scsh+3*256,
                                            nullptr, nullptr, nullptr, nullptr, nullptr, nullptr, nullptr, nullptr, pb1, nb, inv1);
        reduce_fin_kernel<<<128,256,0,stream>>>(pb1, scsh+4*256, G[4], Bv[4], inv1, nb);
        pool_kernel<<<(NCOL2*64)/256,256,0,stream>>>(Cb, X, scsh+4*256, A2);
    }

    // -------- extraction 2: split launches, BN reduce fused into consumer prologue --------
    {
        const float* G[5]  = {pos_bn_g, pos_bn_g+C_, pos_bn_g+2*C_, pos_bn_g+3*C_, pos_ffn_g};
        const float* Bv[5] = {pos_bn_b, pos_bn_b+C_, pos_bn_b+2*C_, pos_bn_b+3*C_, pos_ffn_b};
        const int nb2 = 64;
        conv_mfma<0,0><<<nb2,256,0,stream>>>(A2, nullptr, nullptr, C2, Wq+0*C_*C_, nullptr,
                                             nullptr, nullptr, nullptr, nullptr, nullptr, nullptr, nullptr, nullptr, pbEa, nb2, inv2);
        conv_mfma<1,1><<<nb2,256,0,stream>>>(C2, nullptr, nullptr, C2, Wq+1*C_*C_, nullptr,
                                             nullptr, nullptr, nullptr, nullptr, nullptr, pbEa, G[0], Bv[0], pbEb, nb2, inv2);
        conv_mfma<2,1><<<nb2,256,0,stream>>>(C2, A2, A2, C2, Wq+2*C_*C_, nullptr,
                                             nullptr, nullptr, nullptr, nullptr, nullptr, pbEb, G[1], Bv[1], pbEa, nb2, inv2);
        conv_mfma<1,1><<<nb2,256,0,stream>>>(C2, nullptr, nullptr, C2, Wq+3*C_*C_, nullptr,
                                             nullptr, nullptr, nullptr, nullptr, nullptr, pbEa, G[2], Bv[2], pbEb, nb2, inv2);
        conv_mfma<2,1><<<nb2,256,0,stream>>>(C2, A2, A2, C2, Wq+4*C_*C_, nullptr,
                                             nullptr, nullptr, nullptr, nullptr, nullptr, pbEb, G[3], Bv[3], pbEa, nb2, inv2);
        reduce_fin_kernel<<<128,256,0,stream>>>(pbEa, scsh+5*256, G[4], Bv[4], inv2, nb2);
        out2_kernel<<<64,256,0,stream>>>(C2, A2, scsh+5*256, out_y);
    }
}